// Round 19
// baseline (330.365 us; speedup 1.0000x reference)
//
#include <hip/hip_runtime.h>
#include <hip/hip_bf16.h>
#include <cstdint>

typedef short bf16x8 __attribute__((ext_vector_type(8)));
typedef float f32x4 __attribute__((ext_vector_type(4)));
typedef unsigned short ushort_t;

__device__ __forceinline__ ushort_t f2bf(float f) {
    uint32_t u = __float_as_uint(f);
    u = (u + 0x7fffu + ((u >> 16) & 1u)) >> 16;
    return (ushort_t)u;
}

// native RNE cast; compiler fuses adjacent pairs into v_cvt_pk_bf16_f32 (m240: beats inline asm)
__device__ __forceinline__ ushort_t f2bf_native(float f) {
    __hip_bfloat16 h = __float2bfloat16(f);
    return *reinterpret_cast<ushort_t*>(&h);
}

// async global->LDS, 16B per lane; LDS dest = wave-uniform base + lane*16
__device__ __forceinline__ void gl2lds16(const void* g, void* l) {
    __builtin_amdgcn_global_load_lds((const __attribute__((address_space(1))) void*)(g),
                                     (__attribute__((address_space(3))) void*)(l), 16, 0, 0);
}

__device__ __forceinline__ void wait_vm0() {
    asm volatile("s_waitcnt vmcnt(0)" ::: "memory");
}
// leave the 8 newest vmem ops (probs stores) in flight; older gl2lds drain (FIFO)
__device__ __forceinline__ void wait_vm8() {
    asm volatile("s_waitcnt vmcnt(8)" ::: "memory");
}

// ---------------- fused prep: blocks 0..431 transpose W; blocks 432..6575 convert hidden ----------------
__global__ void prep(const float* __restrict__ hidden, const float* __restrict__ Wq,
                     const float* __restrict__ Wk, const float* __restrict__ Wv,
                     ushort_t* __restrict__ hidB, ushort_t* __restrict__ WtB) {
    __shared__ float tile[64][68];
    int id = blockIdx.x, t = threadIdx.x;
    if (id < 432) {
        int x = id % 12, y = (id / 12) % 12, z = id / 144;
        const float* W = z == 0 ? Wq : (z == 1 ? Wk : Wv);
        int k0 = x * 64, n0 = y * 64;
        for (int i = 0; i < 4; ++i) {
            int e = i * 1024 + t * 4;
            int r = e >> 6, c = e & 63;
            float4 v = *(const float4*)(W + (k0 + r) * 768 + n0 + c);
            *(float4*)(&tile[r][c]) = v;
        }
        __syncthreads();
        ushort_t* o = WtB + z * 589824;
        for (int i = 0; i < 2; ++i) {
            int e = i * 2048 + t * 8;
            int rn = e >> 6, ck = e & 63;
            ushort_t tmp[8] __attribute__((aligned(16)));
            for (int j = 0; j < 8; ++j) tmp[j] = f2bf(tile[ck + j][rn]);
            *(int4*)(o + (n0 + rn) * 768 + k0 + ck) = *(int4*)tmp;
        }
    } else {
        int i = (id - 432) * 256 + t;   // 6144 blocks x 256 = 1572864 float4s exactly
        float4 v = ((const float4*)hidden)[i];
        ushort_t tmp[4] __attribute__((aligned(8)));
        tmp[0] = f2bf(v.x); tmp[1] = f2bf(v.y); tmp[2] = f2bf(v.z); tmp[3] = f2bf(v.w);
        ((uint2*)hidB)[i] = *(uint2*)tmp;
    }
}

// ---------------- QKV GEMM: async gl2lds double-buffered staging, 1 barrier/K-step ----------------
// z==2 (V) writes directly in transposed [bh][d][s] layout (saves the v_transpose pass)
__launch_bounds__(256, 2)
__global__ void qkv_gemm(const ushort_t* __restrict__ A, const ushort_t* __restrict__ Wt,
                         const float* __restrict__ bq, const float* __restrict__ bk,
                         const float* __restrict__ bv,
                         ushort_t* __restrict__ q_out, ushort_t* __restrict__ k_out,
                         ushort_t* __restrict__ vt_out) {
    __shared__ char smem[65536];
    char* sA = smem;            // 2 x 16KB
    char* sB = smem + 32768;    // 2 x 16KB
    int z = blockIdx.z;
    const ushort_t* Wz = Wt + z * 589824;
    const float* bias = z == 0 ? bq : (z == 1 ? bk : bv);
    int m0 = blockIdx.x * 128, n0 = blockIdx.y * 128;
    int t = threadIdx.x, lane = t & 63, w = t >> 6;
    int wr = w >> 1, wc = w & 1;
    int lr = lane & 15, lg = lane >> 4;
    int rsub = lane >> 3;                    // row-in-8 for this lane's 16B chunk
    int jsw  = ((lane & 7) ^ rsub) * 8;      // pre-swizzled source column (elements)

    // prologue: stage K-step 0 (A-tile 128x64 + B-tile 128x64, 16KB each)
#pragma unroll
    for (int i = 0; i < 4; ++i) {
        int r = i * 32 + w * 8 + rsub;
        gl2lds16(A + (m0 + r) * 768 + jsw, sA + i * 4096 + w * 1024);
        gl2lds16(Wz + (n0 + r) * 768 + jsw, sB + i * 4096 + w * 1024);
    }
    wait_vm0();
    __syncthreads();

    f32x4 acc[4][4] = {};
    int cur = 0;
    for (int ktile = 0; ktile < 12; ++ktile) {
        char* sAc = sA + cur * 16384;
        char* sBc = sB + cur * 16384;
        if (ktile < 11) {
            char* sAn = sA + (cur ^ 1) * 16384;
            char* sBn = sB + (cur ^ 1) * 16384;
            int kt = (ktile + 1) * 64;
#pragma unroll
            for (int i = 0; i < 4; ++i) {
                int r = i * 32 + w * 8 + rsub;
                gl2lds16(A + (m0 + r) * 768 + kt + jsw, sAn + i * 4096 + w * 1024);
                gl2lds16(Wz + (n0 + r) * 768 + kt + jsw, sBn + i * 4096 + w * 1024);
            }
        }
        bf16x8 af[2][4], bfr[2][4];
#pragma unroll
        for (int kf = 0; kf < 2; ++kf)
#pragma unroll
            for (int mf = 0; mf < 4; ++mf) {
                int row = wr * 64 + mf * 16 + lr;
                af[kf][mf] = *(const bf16x8*)(sAc + ((row * 128 + (kf * 32 + lg * 8) * 2) ^ ((row & 7) << 4)));
            }
#pragma unroll
        for (int kf = 0; kf < 2; ++kf)
#pragma unroll
            for (int nf = 0; nf < 4; ++nf) {
                int row = wc * 64 + nf * 16 + lr;
                bfr[kf][nf] = *(const bf16x8*)(sBc + ((row * 128 + (kf * 32 + lg * 8) * 2) ^ ((row & 7) << 4)));
            }
        __builtin_amdgcn_s_setprio(1);
#pragma unroll
        for (int kf = 0; kf < 2; ++kf)
#pragma unroll
            for (int mf = 0; mf < 4; ++mf)
#pragma unroll
                for (int nf = 0; nf < 4; ++nf)
                    acc[mf][nf] = __builtin_amdgcn_mfma_f32_16x16x32_bf16(af[kf][mf], bfr[kf][nf], acc[mf][nf], 0, 0, 0);
        __builtin_amdgcn_s_setprio(0);
        wait_vm0();
        __syncthreads();
        cur ^= 1;
    }
    if (z == 2) {
        // V: write transposed vt[bh][d][s]; thread's 4 rr values are s-consecutive -> 8B packed store
        for (int nf = 0; nf < 4; ++nf) {
            int n = n0 + wc * 64 + nf * 16 + lr;
            float bv_ = bias[n];
            int h = n >> 6, d = n & 63;
            for (int mf = 0; mf < 4; ++mf) {
                int m = m0 + wr * 64 + mf * 16 + lg * 4;
                int b = m >> 11, s = m & 2047;
                ushort_t tmp[4] __attribute__((aligned(8)));
                for (int rr = 0; rr < 4; ++rr) tmp[rr] = f2bf(acc[mf][nf][rr] + bv_);
                *(uint2*)(vt_out + ((size_t)(b * 12 + h) * 64 + d) * 2048 + s) = *(uint2*)tmp;
            }
        }
    } else {
        ushort_t* outp = z == 0 ? q_out : k_out;
        float scale = z == 0 ? 0.125f : 1.0f;
        for (int nf = 0; nf < 4; ++nf) {
            int n = n0 + wc * 64 + nf * 16 + lr;
            float bv_ = bias[n];
            int h = n >> 6, d = n & 63;
            for (int mf = 0; mf < 4; ++mf) {
                for (int rr = 0; rr < 4; ++rr) {
                    int m = m0 + wr * 64 + mf * 16 + lg * 4 + rr;
                    float val = (acc[mf][nf][rr] + bv_) * scale;
                    int b = m >> 11, s = m & 2047;
                    outp[((b * 12 + h) * 2048 + s) * 64 + d] = f2bf(val);
                }
            }
        }
    }
}

// ---------------- fused attention: sweep0 = lsum (paired K tiles), sweepB = PV + probs ----------------
// Swapped mfma(K,Q) throughout: lane holds p[q=w*32+mf*16+lr][k=n16*16+lg*4+r].
// sweepB: V fragments loaded DIRECTLY global->register, issued early (T14) -- V staging removed.
// 1-D grid with XCD-aware swizzle (768 % 8 == 0 -> bijective).
__launch_bounds__(256, 3)
__global__ void attn_fused(const ushort_t* __restrict__ qs, const ushort_t* __restrict__ ks,
                           const ushort_t* __restrict__ vt, const float* __restrict__ mask,
                           float* __restrict__ ctx, float* __restrict__ probs) {
    __shared__ char smem[49152];
    char* sK = smem;            // sweepB: 2 x 8KB K dbuf (also Q staging); sweep0: pair-buffers (32KB)
    char* sP = smem + 32768;    // sweepB: 4 waves x 4KB bf16 P
    int id = blockIdx.x;
    int nid = (id & 7) * 96 + (id >> 3);   // XCD swizzle: 8 XCDs x 96 blocks
    int qt = nid & 15, bh = nid >> 4;
    int b = bh / 12, h = bh % 12;
    int q0 = qt * 128;
    int t = threadIdx.x, lane = t & 63, w = t >> 6;
    int lr = lane & 15, lg = lane >> 4;
    const ushort_t* Qb = qs + bh * 131072;
    const ushort_t* Kb = ks + bh * 131072;
    const ushort_t* Vb = vt + bh * 131072;
    const float* mb = mask + b * 2048;
    float* prow = probs + (size_t)bh * 4194304;

    int rsub = lane >> 3;                    // row-in-8 for this lane's 16B chunk
    int jsw  = ((lane & 7) ^ rsub) * 8;      // pre-swizzled source column (elements)

    // stage Q (128x64 = 16KB) into sK area, linear LDS + swizzled source
#pragma unroll
    for (int i = 0; i < 4; ++i) {
        int r = i * 32 + w * 8 + rsub;
        gl2lds16(Qb + (q0 + r) * 64 + jsw, sK + i * 4096 + w * 1024);
    }
    wait_vm0();
    __syncthreads();
    bf16x8 qa[2][2];
#pragma unroll
    for (int mf = 0; mf < 2; ++mf)
#pragma unroll
        for (int kf = 0; kf < 2; ++kf) {
            int row = w * 32 + mf * 16 + lr;
            qa[mf][kf] = *(const bf16x8*)(sK + ((row * 128 + (kf * 32 + lg * 8) * 2) ^ ((row & 7) << 4)));
        }
    __syncthreads();

    // ==== sweep 0: QK^T + exp + row-sum, 2 K-tiles per staging round (16 barriers) ====
#pragma unroll
    for (int t2 = 0; t2 < 2; ++t2)
#pragma unroll
        for (int i = 0; i < 2; ++i) {
            int r = t2 * 64 + i * 32 + w * 8 + rsub;
            gl2lds16(Kb + r * 64 + jsw, smem + t2 * 8192 + i * 4096 + w * 1024);
        }
    wait_vm0();
    __syncthreads();
    float lsum[2] = {0.f, 0.f};
    int cur = 0;
    for (int kp = 0; kp < 16; ++kp) {
        char* bufc = smem + cur * 16384;
        if (kp < 15) {
            char* bufn = smem + (cur ^ 1) * 16384;
#pragma unroll
            for (int t2 = 0; t2 < 2; ++t2)
#pragma unroll
                for (int i = 0; i < 2; ++i) {
                    int r = ((kp + 1) * 2 + t2) * 64 + i * 32 + w * 8 + rsub;
                    gl2lds16(Kb + r * 64 + jsw, bufn + t2 * 8192 + i * 4096 + w * 1024);
                }
        }
#pragma unroll
        for (int t2 = 0; t2 < 2; ++t2) {
            int kt = kp * 2 + t2;
            char* sKc = bufc + t2 * 8192;
#pragma unroll
            for (int n16 = 0; n16 < 4; ++n16) {
                int krow = n16 * 16 + lr;
                bf16x8 kb0 = *(const bf16x8*)(sKc + ((krow * 128 + (lg * 8) * 2) ^ ((krow & 7) << 4)));
                bf16x8 kb1 = *(const bf16x8*)(sKc + ((krow * 128 + (32 + lg * 8) * 2) ^ ((krow & 7) << 4)));
                float4 m4 = *(const float4*)(mb + kt * 64 + n16 * 16 + lg * 4);
                float ma0 = (1.0f - m4.x) * -10000.0f;
                float ma1 = (1.0f - m4.y) * -10000.0f;
                float ma2 = (1.0f - m4.z) * -10000.0f;
                float ma3 = (1.0f - m4.w) * -10000.0f;
#pragma unroll
                for (int mf = 0; mf < 2; ++mf) {
                    f32x4 sacc = {};
                    sacc = __builtin_amdgcn_mfma_f32_16x16x32_bf16(kb0, qa[mf][0], sacc, 0, 0, 0);  // swapped
                    sacc = __builtin_amdgcn_mfma_f32_16x16x32_bf16(kb1, qa[mf][1], sacc, 0, 0, 0);  // swapped
                    lsum[mf] += (__expf(sacc[0] + ma0) + __expf(sacc[1] + ma1))
                              + (__expf(sacc[2] + ma2) + __expf(sacc[3] + ma3));
                }
            }
        }
        wait_vm0();
        __syncthreads();
        cur ^= 1;
    }
    // lane holds partial sum for q = w*32+mf*16+lr over its lg-subset; reduce across lg groups
#pragma unroll
    for (int mf = 0; mf < 2; ++mf) {
        lsum[mf] += __shfl_xor(lsum[mf], 16);
        lsum[mf] += __shfl_xor(lsum[mf], 32);
    }
    float inv2[2] = {1.0f / lsum[0], 1.0f / lsum[1]};

    // ==== sweep B: p (normalized) -> probs + PV; K staged (dbuf), V direct-to-register ====
#pragma unroll
    for (int i = 0; i < 2; ++i) {
        int r = i * 32 + w * 8 + rsub;
        gl2lds16(Kb + r * 64 + jsw, sK + i * 4096 + w * 1024);
    }
    wait_vm0();
    __syncthreads();

    f32x4 oacc[2][4] = {};
    cur = 0;
    for (int kt = 0; kt < 32; ++kt) {
        char* sKc = sK + cur * 8192;
        // V fragments for THIS kt: issue global loads early; consumed after QK^T+sP+probs (~300cy later)
        bf16x8 vreg[2][4];
#pragma unroll
        for (int kf = 0; kf < 2; ++kf)
#pragma unroll
            for (int dt = 0; dt < 4; ++dt)
                vreg[kf][dt] = *(const bf16x8*)(Vb + (dt * 16 + lr) * 2048 + kt * 64 + kf * 32 + lg * 8);
        if (kt < 31) {
            char* sKn = sK + (cur ^ 1) * 8192;
            int nt = kt + 1;
#pragma unroll
            for (int i = 0; i < 2; ++i) {
                int r = i * 32 + w * 8 + rsub;
                gl2lds16(Kb + (nt * 64 + r) * 64 + jsw, sKn + i * 4096 + w * 1024);
            }
        }
        // QK^T (swapped) + exp*inv -> packed bf16 sP writes (native RNE casts -> v_cvt_pk)
#pragma unroll
        for (int n16 = 0; n16 < 4; ++n16) {
            int krow = n16 * 16 + lr;
            bf16x8 kb0 = *(const bf16x8*)(sKc + ((krow * 128 + (lg * 8) * 2) ^ ((krow & 7) << 4)));
            bf16x8 kb1 = *(const bf16x8*)(sKc + ((krow * 128 + (32 + lg * 8) * 2) ^ ((krow & 7) << 4)));
            float4 m4 = *(const float4*)(mb + kt * 64 + n16 * 16 + lg * 4);
            float ma0 = (1.0f - m4.x) * -10000.0f;
            float ma1 = (1.0f - m4.y) * -10000.0f;
            float ma2 = (1.0f - m4.z) * -10000.0f;
            float ma3 = (1.0f - m4.w) * -10000.0f;
#pragma unroll
            for (int mf = 0; mf < 2; ++mf) {
                f32x4 sacc = {};
                sacc = __builtin_amdgcn_mfma_f32_16x16x32_bf16(kb0, qa[mf][0], sacc, 0, 0, 0);  // swapped
                sacc = __builtin_amdgcn_mfma_f32_16x16x32_bf16(kb1, qa[mf][1], sacc, 0, 0, 0);  // swapped
                ushort_t tmp[4] __attribute__((aligned(8)));
                tmp[0] = f2bf_native(__expf(sacc[0] + ma0) * inv2[mf]);
                tmp[1] = f2bf_native(__expf(sacc[1] + ma1) * inv2[mf]);
                tmp[2] = f2bf_native(__expf(sacc[2] + ma2) * inv2[mf]);
                tmp[3] = f2bf_native(__expf(sacc[3] + ma3) * inv2[mf]);
                *(uint2*)(sP + w * 4096 + mf * 2048 +
                          ((lr * 128 + n16 * 32 + lg * 8) ^ ((lr & 7) << 4))) = *(uint2*)tmp;
            }
        }
        // probs FIRST: issue the global stores early so they drain under the PV MFMA below
#pragma unroll
        for (int mf = 0; mf < 2; ++mf)
#pragma unroll
            for (int step = 0; step < 4; ++step) {
                int srow = step * 4 + lg;
                uint2 uu = *(const uint2*)(sP + w * 4096 + mf * 2048 +
                                           ((srow * 128 + lr * 8) ^ ((srow & 7) << 4)));
                f32x4 pv;
                pv[0] = __uint_as_float((uu.x & 0xffffu) << 16);
                pv[1] = __uint_as_float(uu.x & 0xffff0000u);
                pv[2] = __uint_as_float((uu.y & 0xffffu) << 16);
                pv[3] = __uint_as_float(uu.y & 0xffff0000u);
                *(f32x4*)(prow + (size_t)(q0 + w * 32 + mf * 16 + srow) * 2048 + kt * 64 + lr * 4) = pv;
            }
        // PV: pa from sP (byte-identical reads to r4-r18), V from registers
        __builtin_amdgcn_s_setprio(1);
#pragma unroll
        for (int mf = 0; mf < 2; ++mf)
#pragma unroll
            for (int kf = 0; kf < 2; ++kf) {
                bf16x8 pa = *(const bf16x8*)(sP + w * 4096 + mf * 2048 +
                                             ((lr * 128 + (kf * 32 + lg * 8) * 2) ^ ((lr & 7) << 4)));
#pragma unroll
                for (int dt = 0; dt < 4; ++dt)
                    oacc[mf][dt] = __builtin_amdgcn_mfma_f32_16x16x32_bf16(pa, vreg[kf][dt], oacc[mf][dt], 0, 0, 0);
            }
        __builtin_amdgcn_s_setprio(0);
        wait_vm8();        // drain gl2lds (older); keep the 8 probs stores in flight
        __syncthreads();
        cur ^= 1;
    }
    // ctx epilogue: p was pre-normalized, so oacc is the final context
#pragma unroll
    for (int mf = 0; mf < 2; ++mf)
#pragma unroll
        for (int dt = 0; dt < 4; ++dt)
#pragma unroll
            for (int r = 0; r < 4; ++r) {
                int qabs = q0 + w * 32 + mf * 16 + lg * 4 + r;
                ctx[(size_t)(b * 2048 + qabs) * 768 + h * 64 + dt * 16 + lr] = oacc[mf][dt][r];
            }
}

extern "C" void kernel_launch(void* const* d_in, const int* in_sizes, int n_in,
                              void* d_out, int out_size, void* d_ws, size_t ws_size,
                              hipStream_t stream) {
    const float* hidden = (const float*)d_in[0];
    const float* mask   = (const float*)d_in[1];
    const float* Wq     = (const float*)d_in[2];
    const float* bq     = (const float*)d_in[3];
    const float* Wk     = (const float*)d_in[4];
    const float* bk     = (const float*)d_in[5];
    const float* Wv     = (const float*)d_in[6];
    const float* bv     = (const float*)d_in[7];
    float* ctx   = (float*)d_out;
    float* probs = ctx + 6291456;

    char* ws = (char*)d_ws;
    ushort_t* hidB = (ushort_t*)(ws);                 // 12.58 MB
    ushort_t* WtB  = (ushort_t*)(ws + 12582912);      // 3.54 MB
    ushort_t* qsB  = (ushort_t*)(ws + 16121856);      // 12.58 MB
    ushort_t* ksB  = (ushort_t*)(ws + 28704768);      // 12.58 MB
    ushort_t* vtB  = (ushort_t*)(ws + 41287680);      // 12.58 MB (V written pre-transposed)

    hipLaunchKernelGGL(prep, dim3(6576), dim3(256), 0, stream, hidden, Wq, Wk, Wv, hidB, WtB);
    hipLaunchKernelGGL(qkv_gemm, dim3(64, 6, 3), dim3(256), 0, stream,
                       hidB, WtB, bq, bk, bv, qsB, ksB, vtB);
    hipLaunchKernelGGL(attn_fused, dim3(768), dim3(256), 0, stream, qsB, ksB, vtB, mask, ctx, probs);
}

// Round 20
// 262.594 us; speedup vs baseline: 1.2581x; 1.2581x over previous
//
#include <hip/hip_runtime.h>
#include <hip/hip_bf16.h>
#include <cstdint>

typedef short bf16x8 __attribute__((ext_vector_type(8)));
typedef float f32x4 __attribute__((ext_vector_type(4)));
typedef unsigned short ushort_t;

__device__ __forceinline__ ushort_t f2bf(float f) {
    uint32_t u = __float_as_uint(f);
    u = (u + 0x7fffu + ((u >> 16) & 1u)) >> 16;
    return (ushort_t)u;
}

// native RNE cast; compiler fuses adjacent pairs into v_cvt_pk_bf16_f32 (m240: beats inline asm)
__device__ __forceinline__ ushort_t f2bf_native(float f) {
    __hip_bfloat16 h = __float2bfloat16(f);
    return *reinterpret_cast<ushort_t*>(&h);
}

// async global->LDS, 16B per lane; LDS dest = wave-uniform base + lane*16
__device__ __forceinline__ void gl2lds16(const void* g, void* l) {
    __builtin_amdgcn_global_load_lds((const __attribute__((address_space(1))) void*)(g),
                                     (__attribute__((address_space(3))) void*)(l), 16, 0, 0);
}

__device__ __forceinline__ void wait_vm0() {
    asm volatile("s_waitcnt vmcnt(0)" ::: "memory");
}
// leave the 8 newest vmem ops (probs stores) in flight; older gl2lds drain (FIFO)
__device__ __forceinline__ void wait_vm8() {
    asm volatile("s_waitcnt vmcnt(8)" ::: "memory");
}

// ---------------- fused prep: blocks 0..431 transpose W; blocks 432..6575 convert hidden ----------------
__global__ void prep(const float* __restrict__ hidden, const float* __restrict__ Wq,
                     const float* __restrict__ Wk, const float* __restrict__ Wv,
                     ushort_t* __restrict__ hidB, ushort_t* __restrict__ WtB) {
    __shared__ float tile[64][68];
    int id = blockIdx.x, t = threadIdx.x;
    if (id < 432) {
        int x = id % 12, y = (id / 12) % 12, z = id / 144;
        const float* W = z == 0 ? Wq : (z == 1 ? Wk : Wv);
        int k0 = x * 64, n0 = y * 64;
        for (int i = 0; i < 4; ++i) {
            int e = i * 1024 + t * 4;
            int r = e >> 6, c = e & 63;
            float4 v = *(const float4*)(W + (k0 + r) * 768 + n0 + c);
            *(float4*)(&tile[r][c]) = v;
        }
        __syncthreads();
        ushort_t* o = WtB + z * 589824;
        for (int i = 0; i < 2; ++i) {
            int e = i * 2048 + t * 8;
            int rn = e >> 6, ck = e & 63;
            ushort_t tmp[8] __attribute__((aligned(16)));
            for (int j = 0; j < 8; ++j) tmp[j] = f2bf(tile[ck + j][rn]);
            *(int4*)(o + (n0 + rn) * 768 + k0 + ck) = *(int4*)tmp;
        }
    } else {
        int i = (id - 432) * 256 + t;   // 6144 blocks x 256 = 1572864 float4s exactly
        float4 v = ((const float4*)hidden)[i];
        ushort_t tmp[4] __attribute__((aligned(8)));
        tmp[0] = f2bf(v.x); tmp[1] = f2bf(v.y); tmp[2] = f2bf(v.z); tmp[3] = f2bf(v.w);
        ((uint2*)hidB)[i] = *(uint2*)tmp;
    }
}

// ---------------- QKV GEMM: async gl2lds double-buffered staging, 1 barrier/K-step ----------------
// z==2 (V) writes directly in transposed [bh][d][s] layout (saves the v_transpose pass)
__launch_bounds__(256, 2)
__global__ void qkv_gemm(const ushort_t* __restrict__ A, const ushort_t* __restrict__ Wt,
                         const float* __restrict__ bq, const float* __restrict__ bk,
                         const float* __restrict__ bv,
                         ushort_t* __restrict__ q_out, ushort_t* __restrict__ k_out,
                         ushort_t* __restrict__ vt_out) {
    __shared__ char smem[65536];
    char* sA = smem;            // 2 x 16KB
    char* sB = smem + 32768;    // 2 x 16KB
    int z = blockIdx.z;
    const ushort_t* Wz = Wt + z * 589824;
    const float* bias = z == 0 ? bq : (z == 1 ? bk : bv);
    int m0 = blockIdx.x * 128, n0 = blockIdx.y * 128;
    int t = threadIdx.x, lane = t & 63, w = t >> 6;
    int wr = w >> 1, wc = w & 1;
    int lr = lane & 15, lg = lane >> 4;
    int rsub = lane >> 3;                    // row-in-8 for this lane's 16B chunk
    int jsw  = ((lane & 7) ^ rsub) * 8;      // pre-swizzled source column (elements)

    // prologue: stage K-step 0 (A-tile 128x64 + B-tile 128x64, 16KB each)
#pragma unroll
    for (int i = 0; i < 4; ++i) {
        int r = i * 32 + w * 8 + rsub;
        gl2lds16(A + (m0 + r) * 768 + jsw, sA + i * 4096 + w * 1024);
        gl2lds16(Wz + (n0 + r) * 768 + jsw, sB + i * 4096 + w * 1024);
    }
    wait_vm0();
    __syncthreads();

    f32x4 acc[4][4] = {};
    int cur = 0;
    for (int ktile = 0; ktile < 12; ++ktile) {
        char* sAc = sA + cur * 16384;
        char* sBc = sB + cur * 16384;
        if (ktile < 11) {
            char* sAn = sA + (cur ^ 1) * 16384;
            char* sBn = sB + (cur ^ 1) * 16384;
            int kt = (ktile + 1) * 64;
#pragma unroll
            for (int i = 0; i < 4; ++i) {
                int r = i * 32 + w * 8 + rsub;
                gl2lds16(A + (m0 + r) * 768 + kt + jsw, sAn + i * 4096 + w * 1024);
                gl2lds16(Wz + (n0 + r) * 768 + kt + jsw, sBn + i * 4096 + w * 1024);
            }
        }
        bf16x8 af[2][4], bfr[2][4];
#pragma unroll
        for (int kf = 0; kf < 2; ++kf)
#pragma unroll
            for (int mf = 0; mf < 4; ++mf) {
                int row = wr * 64 + mf * 16 + lr;
                af[kf][mf] = *(const bf16x8*)(sAc + ((row * 128 + (kf * 32 + lg * 8) * 2) ^ ((row & 7) << 4)));
            }
#pragma unroll
        for (int kf = 0; kf < 2; ++kf)
#pragma unroll
            for (int nf = 0; nf < 4; ++nf) {
                int row = wc * 64 + nf * 16 + lr;
                bfr[kf][nf] = *(const bf16x8*)(sBc + ((row * 128 + (kf * 32 + lg * 8) * 2) ^ ((row & 7) << 4)));
            }
        __builtin_amdgcn_s_setprio(1);
#pragma unroll
        for (int kf = 0; kf < 2; ++kf)
#pragma unroll
            for (int mf = 0; mf < 4; ++mf)
#pragma unroll
                for (int nf = 0; nf < 4; ++nf)
                    acc[mf][nf] = __builtin_amdgcn_mfma_f32_16x16x32_bf16(af[kf][mf], bfr[kf][nf], acc[mf][nf], 0, 0, 0);
        __builtin_amdgcn_s_setprio(0);
        wait_vm0();
        __syncthreads();
        cur ^= 1;
    }
    if (z == 2) {
        // V: write transposed vt[bh][d][s]; thread's 4 rr values are s-consecutive -> 8B packed store
        for (int nf = 0; nf < 4; ++nf) {
            int n = n0 + wc * 64 + nf * 16 + lr;
            float bv_ = bias[n];
            int h = n >> 6, d = n & 63;
            for (int mf = 0; mf < 4; ++mf) {
                int m = m0 + wr * 64 + mf * 16 + lg * 4;
                int b = m >> 11, s = m & 2047;
                ushort_t tmp[4] __attribute__((aligned(8)));
                for (int rr = 0; rr < 4; ++rr) tmp[rr] = f2bf(acc[mf][nf][rr] + bv_);
                *(uint2*)(vt_out + ((size_t)(b * 12 + h) * 64 + d) * 2048 + s) = *(uint2*)tmp;
            }
        }
    } else {
        ushort_t* outp = z == 0 ? q_out : k_out;
        float scale = z == 0 ? 0.125f : 1.0f;
        for (int nf = 0; nf < 4; ++nf) {
            int n = n0 + wc * 64 + nf * 16 + lr;
            float bv_ = bias[n];
            int h = n >> 6, d = n & 63;
            for (int mf = 0; mf < 4; ++mf) {
                for (int rr = 0; rr < 4; ++rr) {
                    int m = m0 + wr * 64 + mf * 16 + lg * 4 + rr;
                    float val = (acc[mf][nf][rr] + bv_) * scale;
                    int b = m >> 11, s = m & 2047;
                    outp[((b * 12 + h) * 2048 + s) * 64 + d] = f2bf(val);
                }
            }
        }
    }
}

// ---------------- fused attention: sweep0 = lsum (paired K tiles), sweepB = PV + probs ----------------
// Swapped mfma(K,Q) throughout: lane holds p[q=w*32+mf*16+lr][k=n16*16+lg*4+r].
// 1-D grid with XCD-aware swizzle (768 % 8 == 0 -> bijective): groups 6 consecutive bh per XCD
// so K/V (3MB) stays in that XCD's L2 instead of being fetched 8x.
__launch_bounds__(256, 3)
__global__ void attn_fused(const ushort_t* __restrict__ qs, const ushort_t* __restrict__ ks,
                           const ushort_t* __restrict__ vt, const float* __restrict__ mask,
                           float* __restrict__ ctx, float* __restrict__ probs) {
    __shared__ char smem[49152];
    char* sK = smem;            // sweepB: 2 x 8KB K dbuf (also Q staging); sweep0: pair-buffer 0 (16KB)
    char* sV = smem + 16384;    // sweepB: 2 x 8KB V dbuf; sweep0: pair-buffer 1 (16KB)
    char* sP = smem + 32768;    // sweepB: 4 waves x 4KB bf16 P
    int id = blockIdx.x;
    int nid = (id & 7) * 96 + (id >> 3);   // XCD swizzle: 8 XCDs x 96 blocks
    int qt = nid & 15, bh = nid >> 4;
    int b = bh / 12, h = bh % 12;
    int q0 = qt * 128;
    int t = threadIdx.x, lane = t & 63, w = t >> 6;
    int lr = lane & 15, lg = lane >> 4;
    const ushort_t* Qb = qs + bh * 131072;
    const ushort_t* Kb = ks + bh * 131072;
    const ushort_t* Vb = vt + bh * 131072;
    const float* mb = mask + b * 2048;
    float* prow = probs + (size_t)bh * 4194304;

    int rsub = lane >> 3;                    // row-in-8 for this lane's 16B chunk
    int jsw  = ((lane & 7) ^ rsub) * 8;      // pre-swizzled source column (elements)

    // stage Q (128x64 = 16KB) into sK area, linear LDS + swizzled source
#pragma unroll
    for (int i = 0; i < 4; ++i) {
        int r = i * 32 + w * 8 + rsub;
        gl2lds16(Qb + (q0 + r) * 64 + jsw, sK + i * 4096 + w * 1024);
    }
    wait_vm0();
    __syncthreads();
    bf16x8 qa[2][2];
#pragma unroll
    for (int mf = 0; mf < 2; ++mf)
#pragma unroll
        for (int kf = 0; kf < 2; ++kf) {
            int row = w * 32 + mf * 16 + lr;
            qa[mf][kf] = *(const bf16x8*)(sK + ((row * 128 + (kf * 32 + lg * 8) * 2) ^ ((row & 7) << 4)));
        }
    __syncthreads();

    // ==== sweep 0: QK^T + exp + row-sum, 2 K-tiles per staging round (16 barriers) ====
#pragma unroll
    for (int t2 = 0; t2 < 2; ++t2)
#pragma unroll
        for (int i = 0; i < 2; ++i) {
            int r = t2 * 64 + i * 32 + w * 8 + rsub;
            gl2lds16(Kb + r * 64 + jsw, smem + t2 * 8192 + i * 4096 + w * 1024);
        }
    wait_vm0();
    __syncthreads();
    float lsum[2] = {0.f, 0.f};
    int cur = 0;
    for (int kp = 0; kp < 16; ++kp) {
        char* bufc = smem + cur * 16384;
        if (kp < 15) {
            char* bufn = smem + (cur ^ 1) * 16384;
#pragma unroll
            for (int t2 = 0; t2 < 2; ++t2)
#pragma unroll
                for (int i = 0; i < 2; ++i) {
                    int r = ((kp + 1) * 2 + t2) * 64 + i * 32 + w * 8 + rsub;
                    gl2lds16(Kb + r * 64 + jsw, bufn + t2 * 8192 + i * 4096 + w * 1024);
                }
        }
#pragma unroll
        for (int t2 = 0; t2 < 2; ++t2) {
            int kt = kp * 2 + t2;
            char* sKc = bufc + t2 * 8192;
#pragma unroll
            for (int n16 = 0; n16 < 4; ++n16) {
                int krow = n16 * 16 + lr;
                bf16x8 kb0 = *(const bf16x8*)(sKc + ((krow * 128 + (lg * 8) * 2) ^ ((krow & 7) << 4)));
                bf16x8 kb1 = *(const bf16x8*)(sKc + ((krow * 128 + (32 + lg * 8) * 2) ^ ((krow & 7) << 4)));
                float4 m4 = *(const float4*)(mb + kt * 64 + n16 * 16 + lg * 4);
                float ma0 = (1.0f - m4.x) * -10000.0f;
                float ma1 = (1.0f - m4.y) * -10000.0f;
                float ma2 = (1.0f - m4.z) * -10000.0f;
                float ma3 = (1.0f - m4.w) * -10000.0f;
#pragma unroll
                for (int mf = 0; mf < 2; ++mf) {
                    f32x4 sacc = {};
                    sacc = __builtin_amdgcn_mfma_f32_16x16x32_bf16(kb0, qa[mf][0], sacc, 0, 0, 0);  // swapped
                    sacc = __builtin_amdgcn_mfma_f32_16x16x32_bf16(kb1, qa[mf][1], sacc, 0, 0, 0);  // swapped
                    lsum[mf] += (__expf(sacc[0] + ma0) + __expf(sacc[1] + ma1))
                              + (__expf(sacc[2] + ma2) + __expf(sacc[3] + ma3));
                }
            }
        }
        wait_vm0();
        __syncthreads();
        cur ^= 1;
    }
    // lane holds partial sum for q = w*32+mf*16+lr over its lg-subset; reduce across lg groups
#pragma unroll
    for (int mf = 0; mf < 2; ++mf) {
        lsum[mf] += __shfl_xor(lsum[mf], 16);
        lsum[mf] += __shfl_xor(lsum[mf], 32);
    }
    float inv2[2] = {1.0f / lsum[0], 1.0f / lsum[1]};

    // ==== sweep B: p (normalized) -> probs + PV, one pass ====
#pragma unroll
    for (int i = 0; i < 2; ++i) {
        int r = i * 32 + w * 8 + rsub;
        gl2lds16(Kb + r * 64 + jsw, sK + i * 4096 + w * 1024);
        gl2lds16(Vb + r * 2048 + jsw, sV + i * 4096 + w * 1024);
    }
    wait_vm0();
    __syncthreads();

    f32x4 oacc[2][4] = {};
    cur = 0;
    for (int kt = 0; kt < 32; ++kt) {
        char* sKc = sK + cur * 8192;
        char* sVc = sV + cur * 8192;
        if (kt < 31) {
            char* sKn = sK + (cur ^ 1) * 8192;
            char* sVn = sV + (cur ^ 1) * 8192;
            int nt = kt + 1;
#pragma unroll
            for (int i = 0; i < 2; ++i) {
                int r = i * 32 + w * 8 + rsub;
                gl2lds16(Kb + (nt * 64 + r) * 64 + jsw, sKn + i * 4096 + w * 1024);
                gl2lds16(Vb + r * 2048 + nt * 64 + jsw, sVn + i * 4096 + w * 1024);
            }
        }
        // QK^T (swapped) + exp*inv -> packed bf16 sP writes (native RNE casts -> v_cvt_pk)
#pragma unroll
        for (int n16 = 0; n16 < 4; ++n16) {
            int krow = n16 * 16 + lr;
            bf16x8 kb0 = *(const bf16x8*)(sKc + ((krow * 128 + (lg * 8) * 2) ^ ((krow & 7) << 4)));
            bf16x8 kb1 = *(const bf16x8*)(sKc + ((krow * 128 + (32 + lg * 8) * 2) ^ ((krow & 7) << 4)));
            float4 m4 = *(const float4*)(mb + kt * 64 + n16 * 16 + lg * 4);
            float ma0 = (1.0f - m4.x) * -10000.0f;
            float ma1 = (1.0f - m4.y) * -10000.0f;
            float ma2 = (1.0f - m4.z) * -10000.0f;
            float ma3 = (1.0f - m4.w) * -10000.0f;
#pragma unroll
            for (int mf = 0; mf < 2; ++mf) {
                f32x4 sacc = {};
                sacc = __builtin_amdgcn_mfma_f32_16x16x32_bf16(kb0, qa[mf][0], sacc, 0, 0, 0);  // swapped
                sacc = __builtin_amdgcn_mfma_f32_16x16x32_bf16(kb1, qa[mf][1], sacc, 0, 0, 0);  // swapped
                ushort_t tmp[4] __attribute__((aligned(8)));
                tmp[0] = f2bf_native(__expf(sacc[0] + ma0) * inv2[mf]);
                tmp[1] = f2bf_native(__expf(sacc[1] + ma1) * inv2[mf]);
                tmp[2] = f2bf_native(__expf(sacc[2] + ma2) * inv2[mf]);
                tmp[3] = f2bf_native(__expf(sacc[3] + ma3) * inv2[mf]);
                *(uint2*)(sP + w * 4096 + mf * 2048 +
                          ((lr * 128 + n16 * 32 + lg * 8) ^ ((lr & 7) << 4))) = *(uint2*)tmp;
            }
        }
        // probs FIRST: issue the global stores early so they drain under the PV MFMA below
#pragma unroll
        for (int mf = 0; mf < 2; ++mf)
#pragma unroll
            for (int step = 0; step < 4; ++step) {
                int srow = step * 4 + lg;
                uint2 uu = *(const uint2*)(sP + w * 4096 + mf * 2048 +
                                           ((srow * 128 + lr * 8) ^ ((srow & 7) << 4)));
                f32x4 pv;
                pv[0] = __uint_as_float((uu.x & 0xffffu) << 16);
                pv[1] = __uint_as_float(uu.x & 0xffff0000u);
                pv[2] = __uint_as_float((uu.y & 0xffffu) << 16);
                pv[3] = __uint_as_float(uu.y & 0xffff0000u);
                *(f32x4*)(prow + (size_t)(q0 + w * 32 + mf * 16 + srow) * 2048 + kt * 64 + lr * 4) = pv;
            }
        // PV (byte-identical reads to r4-r17)
        __builtin_amdgcn_s_setprio(1);
#pragma unroll
        for (int mf = 0; mf < 2; ++mf)
#pragma unroll
            for (int kf = 0; kf < 2; ++kf) {
                bf16x8 pa = *(const bf16x8*)(sP + w * 4096 + mf * 2048 +
                                             ((lr * 128 + (kf * 32 + lg * 8) * 2) ^ ((lr & 7) << 4)));
#pragma unroll
                for (int dt = 0; dt < 4; ++dt) {
                    int vrow = dt * 16 + lr;
                    bf16x8 vb = *(const bf16x8*)(sVc + ((vrow * 128 + (kf * 32 + lg * 8) * 2) ^ ((vrow & 7) << 4)));
                    oacc[mf][dt] = __builtin_amdgcn_mfma_f32_16x16x32_bf16(pa, vb, oacc[mf][dt], 0, 0, 0);
                }
            }
        __builtin_amdgcn_s_setprio(0);
        wait_vm8();        // drain gl2lds (older); keep the 8 probs stores in flight
        __syncthreads();
        cur ^= 1;
    }
    // ctx epilogue: p was pre-normalized, so oacc is the final context
#pragma unroll
    for (int mf = 0; mf < 2; ++mf)
#pragma unroll
        for (int dt = 0; dt < 4; ++dt)
#pragma unroll
            for (int r = 0; r < 4; ++r) {
                int qabs = q0 + w * 32 + mf * 16 + lg * 4 + r;
                ctx[(size_t)(b * 2048 + qabs) * 768 + h * 64 + dt * 16 + lr] = oacc[mf][dt][r];
            }
}

extern "C" void kernel_launch(void* const* d_in, const int* in_sizes, int n_in,
                              void* d_out, int out_size, void* d_ws, size_t ws_size,
                              hipStream_t stream) {
    const float* hidden = (const float*)d_in[0];
    const float* mask   = (const float*)d_in[1];
    const float* Wq     = (const float*)d_in[2];
    const float* bq     = (const float*)d_in[3];
    const float* Wk     = (const float*)d_in[4];
    const float* bk     = (const float*)d_in[5];
    const float* Wv     = (const float*)d_in[6];
    const float* bv     = (const float*)d_in[7];
    float* ctx   = (float*)d_out;
    float* probs = ctx + 6291456;

    char* ws = (char*)d_ws;
    ushort_t* hidB = (ushort_t*)(ws);                 // 12.58 MB
    ushort_t* WtB  = (ushort_t*)(ws + 12582912);      // 3.54 MB
    ushort_t* qsB  = (ushort_t*)(ws + 16121856);      // 12.58 MB
    ushort_t* ksB  = (ushort_t*)(ws + 28704768);      // 12.58 MB
    ushort_t* vtB  = (ushort_t*)(ws + 41287680);      // 12.58 MB (V written pre-transposed)

    hipLaunchKernelGGL(prep, dim3(6576), dim3(256), 0, stream, hidden, Wq, Wk, Wv, hidB, WtB);
    hipLaunchKernelGGL(qkv_gemm, dim3(64, 6, 3), dim3(256), 0, stream,
                       hidB, WtB, bq, bk, bv, qsB, ksB, vtB);
    hipLaunchKernelGGL(attn_fused, dim3(768), dim3(256), 0, stream, qsB, ksB, vtB, mask, ctx, probs);
}

// Round 21
// 246.666 us; speedup vs baseline: 1.3393x; 1.0646x over previous
//
#include <hip/hip_runtime.h>
#include <hip/hip_bf16.h>
#include <cstdint>

typedef short bf16x8 __attribute__((ext_vector_type(8)));
typedef float f32x4 __attribute__((ext_vector_type(4)));
typedef unsigned short ushort_t;

__device__ __forceinline__ ushort_t f2bf(float f) {
    uint32_t u = __float_as_uint(f);
    u = (u + 0x7fffu + ((u >> 16) & 1u)) >> 16;
    return (ushort_t)u;
}

// native RNE cast; compiler fuses adjacent pairs into v_cvt_pk_bf16_f32 (m240: beats inline asm)
__device__ __forceinline__ ushort_t f2bf_native(float f) {
    __hip_bfloat16 h = __float2bfloat16(f);
    return *reinterpret_cast<ushort_t*>(&h);
}

// async global->LDS, 16B per lane; LDS dest = wave-uniform base + lane*16
__device__ __forceinline__ void gl2lds16(const void* g, void* l) {
    __builtin_amdgcn_global_load_lds((const __attribute__((address_space(1))) void*)(g),
                                     (__attribute__((address_space(3))) void*)(l), 16, 0, 0);
}

__device__ __forceinline__ void wait_vm0() {
    asm volatile("s_waitcnt vmcnt(0)" ::: "memory");
}
// leave the 8 newest vmem ops (probs stores) in flight; older gl2lds drain (FIFO)
__device__ __forceinline__ void wait_vm8() {
    asm volatile("s_waitcnt vmcnt(8)" ::: "memory");
}

// ---------------- fused prep: blocks 0..431 transpose W; blocks 432..6575 convert hidden ----------------
__global__ void prep(const float* __restrict__ hidden, const float* __restrict__ Wq,
                     const float* __restrict__ Wk, const float* __restrict__ Wv,
                     ushort_t* __restrict__ hidB, ushort_t* __restrict__ WtB) {
    __shared__ float tile[64][68];
    int id = blockIdx.x, t = threadIdx.x;
    if (id < 432) {
        int x = id % 12, y = (id / 12) % 12, z = id / 144;
        const float* W = z == 0 ? Wq : (z == 1 ? Wk : Wv);
        int k0 = x * 64, n0 = y * 64;
        for (int i = 0; i < 4; ++i) {
            int e = i * 1024 + t * 4;
            int r = e >> 6, c = e & 63;
            float4 v = *(const float4*)(W + (k0 + r) * 768 + n0 + c);
            *(float4*)(&tile[r][c]) = v;
        }
        __syncthreads();
        ushort_t* o = WtB + z * 589824;
        for (int i = 0; i < 2; ++i) {
            int e = i * 2048 + t * 8;
            int rn = e >> 6, ck = e & 63;
            ushort_t tmp[8] __attribute__((aligned(16)));
            for (int j = 0; j < 8; ++j) tmp[j] = f2bf(tile[ck + j][rn]);
            *(int4*)(o + (n0 + rn) * 768 + k0 + ck) = *(int4*)tmp;
        }
    } else {
        int i = (id - 432) * 256 + t;   // 6144 blocks x 256 = 1572864 float4s exactly
        float4 v = ((const float4*)hidden)[i];
        ushort_t tmp[4] __attribute__((aligned(8)));
        tmp[0] = f2bf(v.x); tmp[1] = f2bf(v.y); tmp[2] = f2bf(v.z); tmp[3] = f2bf(v.w);
        ((uint2*)hidB)[i] = *(uint2*)tmp;
    }
}

// ---------------- QKV GEMM: async gl2lds double-buffered staging, 1 barrier/K-step ----------------
// z==2 (V) writes directly in transposed [bh][d][s] layout (saves the v_transpose pass)
__launch_bounds__(256, 2)
__global__ void qkv_gemm(const ushort_t* __restrict__ A, const ushort_t* __restrict__ Wt,
                         const float* __restrict__ bq, const float* __restrict__ bk,
                         const float* __restrict__ bv,
                         ushort_t* __restrict__ q_out, ushort_t* __restrict__ k_out,
                         ushort_t* __restrict__ vt_out) {
    __shared__ char smem[65536];
    char* sA = smem;            // 2 x 16KB
    char* sB = smem + 32768;    // 2 x 16KB
    int z = blockIdx.z;
    const ushort_t* Wz = Wt + z * 589824;
    const float* bias = z == 0 ? bq : (z == 1 ? bk : bv);
    int m0 = blockIdx.x * 128, n0 = blockIdx.y * 128;
    int t = threadIdx.x, lane = t & 63, w = t >> 6;
    int wr = w >> 1, wc = w & 1;
    int lr = lane & 15, lg = lane >> 4;
    int rsub = lane >> 3;                    // row-in-8 for this lane's 16B chunk
    int jsw  = ((lane & 7) ^ rsub) * 8;      // pre-swizzled source column (elements)

    // prologue: stage K-step 0 (A-tile 128x64 + B-tile 128x64, 16KB each)
#pragma unroll
    for (int i = 0; i < 4; ++i) {
        int r = i * 32 + w * 8 + rsub;
        gl2lds16(A + (m0 + r) * 768 + jsw, sA + i * 4096 + w * 1024);
        gl2lds16(Wz + (n0 + r) * 768 + jsw, sB + i * 4096 + w * 1024);
    }
    wait_vm0();
    __syncthreads();

    f32x4 acc[4][4] = {};
    int cur = 0;
    for (int ktile = 0; ktile < 12; ++ktile) {
        char* sAc = sA + cur * 16384;
        char* sBc = sB + cur * 16384;
        if (ktile < 11) {
            char* sAn = sA + (cur ^ 1) * 16384;
            char* sBn = sB + (cur ^ 1) * 16384;
            int kt = (ktile + 1) * 64;
#pragma unroll
            for (int i = 0; i < 4; ++i) {
                int r = i * 32 + w * 8 + rsub;
                gl2lds16(A + (m0 + r) * 768 + kt + jsw, sAn + i * 4096 + w * 1024);
                gl2lds16(Wz + (n0 + r) * 768 + kt + jsw, sBn + i * 4096 + w * 1024);
            }
        }
        bf16x8 af[2][4], bfr[2][4];
#pragma unroll
        for (int kf = 0; kf < 2; ++kf)
#pragma unroll
            for (int mf = 0; mf < 4; ++mf) {
                int row = wr * 64 + mf * 16 + lr;
                af[kf][mf] = *(const bf16x8*)(sAc + ((row * 128 + (kf * 32 + lg * 8) * 2) ^ ((row & 7) << 4)));
            }
#pragma unroll
        for (int kf = 0; kf < 2; ++kf)
#pragma unroll
            for (int nf = 0; nf < 4; ++nf) {
                int row = wc * 64 + nf * 16 + lr;
                bfr[kf][nf] = *(const bf16x8*)(sBc + ((row * 128 + (kf * 32 + lg * 8) * 2) ^ ((row & 7) << 4)));
            }
        __builtin_amdgcn_s_setprio(1);
#pragma unroll
        for (int kf = 0; kf < 2; ++kf)
#pragma unroll
            for (int mf = 0; mf < 4; ++mf)
#pragma unroll
                for (int nf = 0; nf < 4; ++nf)
                    acc[mf][nf] = __builtin_amdgcn_mfma_f32_16x16x32_bf16(af[kf][mf], bfr[kf][nf], acc[mf][nf], 0, 0, 0);
        __builtin_amdgcn_s_setprio(0);
        wait_vm0();
        __syncthreads();
        cur ^= 1;
    }
    if (z == 2) {
        // V: write transposed vt[bh][d][s]; thread's 4 rr values are s-consecutive -> 8B packed store
        for (int nf = 0; nf < 4; ++nf) {
            int n = n0 + wc * 64 + nf * 16 + lr;
            float bv_ = bias[n];
            int h = n >> 6, d = n & 63;
            for (int mf = 0; mf < 4; ++mf) {
                int m = m0 + wr * 64 + mf * 16 + lg * 4;
                int b = m >> 11, s = m & 2047;
                ushort_t tmp[4] __attribute__((aligned(8)));
                for (int rr = 0; rr < 4; ++rr) tmp[rr] = f2bf(acc[mf][nf][rr] + bv_);
                *(uint2*)(vt_out + ((size_t)(b * 12 + h) * 64 + d) * 2048 + s) = *(uint2*)tmp;
            }
        }
    } else {
        ushort_t* outp = z == 0 ? q_out : k_out;
        float scale = z == 0 ? 0.125f : 1.0f;
        for (int nf = 0; nf < 4; ++nf) {
            int n = n0 + wc * 64 + nf * 16 + lr;
            float bv_ = bias[n];
            int h = n >> 6, d = n & 63;
            for (int mf = 0; mf < 4; ++mf) {
                for (int rr = 0; rr < 4; ++rr) {
                    int m = m0 + wr * 64 + mf * 16 + lg * 4 + rr;
                    float val = (acc[mf][nf][rr] + bv_) * scale;
                    int b = m >> 11, s = m & 2047;
                    outp[((b * 12 + h) * 2048 + s) * 64 + d] = f2bf(val);
                }
            }
        }
    }
}

// ---------------- fused attention: sweep0 = lsum (paired K tiles), sweepB = PV + probs ----------------
// Swapped mfma(K,Q) throughout: lane holds p[q=w*32+mf*16+lr][k=n16*16+lg*4+r].
// probs/ctx use NONTEMPORAL stores: 805MB write-once stream bypasses L2, keeping K/V resident.
// 1-D grid with XCD-aware swizzle (768 % 8 == 0 -> bijective).
__launch_bounds__(256, 3)
__global__ void attn_fused(const ushort_t* __restrict__ qs, const ushort_t* __restrict__ ks,
                           const ushort_t* __restrict__ vt, const float* __restrict__ mask,
                           float* __restrict__ ctx, float* __restrict__ probs) {
    __shared__ char smem[49152];
    char* sK = smem;            // sweepB: 2 x 8KB K dbuf (also Q staging); sweep0: pair-buffer 0 (16KB)
    char* sV = smem + 16384;    // sweepB: 2 x 8KB V dbuf; sweep0: pair-buffer 1 (16KB)
    char* sP = smem + 32768;    // sweepB: 4 waves x 4KB bf16 P
    int id = blockIdx.x;
    int nid = (id & 7) * 96 + (id >> 3);   // XCD swizzle: 8 XCDs x 96 blocks
    int qt = nid & 15, bh = nid >> 4;
    int b = bh / 12, h = bh % 12;
    int q0 = qt * 128;
    int t = threadIdx.x, lane = t & 63, w = t >> 6;
    int lr = lane & 15, lg = lane >> 4;
    const ushort_t* Qb = qs + bh * 131072;
    const ushort_t* Kb = ks + bh * 131072;
    const ushort_t* Vb = vt + bh * 131072;
    const float* mb = mask + b * 2048;
    float* prow = probs + (size_t)bh * 4194304;

    int rsub = lane >> 3;                    // row-in-8 for this lane's 16B chunk
    int jsw  = ((lane & 7) ^ rsub) * 8;      // pre-swizzled source column (elements)

    // stage Q (128x64 = 16KB) into sK area, linear LDS + swizzled source
#pragma unroll
    for (int i = 0; i < 4; ++i) {
        int r = i * 32 + w * 8 + rsub;
        gl2lds16(Qb + (q0 + r) * 64 + jsw, sK + i * 4096 + w * 1024);
    }
    wait_vm0();
    __syncthreads();
    bf16x8 qa[2][2];
#pragma unroll
    for (int mf = 0; mf < 2; ++mf)
#pragma unroll
        for (int kf = 0; kf < 2; ++kf) {
            int row = w * 32 + mf * 16 + lr;
            qa[mf][kf] = *(const bf16x8*)(sK + ((row * 128 + (kf * 32 + lg * 8) * 2) ^ ((row & 7) << 4)));
        }
    __syncthreads();

    // ==== sweep 0: QK^T + exp + row-sum, 2 K-tiles per staging round (16 barriers) ====
#pragma unroll
    for (int t2 = 0; t2 < 2; ++t2)
#pragma unroll
        for (int i = 0; i < 2; ++i) {
            int r = t2 * 64 + i * 32 + w * 8 + rsub;
            gl2lds16(Kb + r * 64 + jsw, smem + t2 * 8192 + i * 4096 + w * 1024);
        }
    wait_vm0();
    __syncthreads();
    float lsum[2] = {0.f, 0.f};
    int cur = 0;
    for (int kp = 0; kp < 16; ++kp) {
        char* bufc = smem + cur * 16384;
        if (kp < 15) {
            char* bufn = smem + (cur ^ 1) * 16384;
#pragma unroll
            for (int t2 = 0; t2 < 2; ++t2)
#pragma unroll
                for (int i = 0; i < 2; ++i) {
                    int r = ((kp + 1) * 2 + t2) * 64 + i * 32 + w * 8 + rsub;
                    gl2lds16(Kb + r * 64 + jsw, bufn + t2 * 8192 + i * 4096 + w * 1024);
                }
        }
#pragma unroll
        for (int t2 = 0; t2 < 2; ++t2) {
            int kt = kp * 2 + t2;
            char* sKc = bufc + t2 * 8192;
#pragma unroll
            for (int n16 = 0; n16 < 4; ++n16) {
                int krow = n16 * 16 + lr;
                bf16x8 kb0 = *(const bf16x8*)(sKc + ((krow * 128 + (lg * 8) * 2) ^ ((krow & 7) << 4)));
                bf16x8 kb1 = *(const bf16x8*)(sKc + ((krow * 128 + (32 + lg * 8) * 2) ^ ((krow & 7) << 4)));
                float4 m4 = *(const float4*)(mb + kt * 64 + n16 * 16 + lg * 4);
                float ma0 = (1.0f - m4.x) * -10000.0f;
                float ma1 = (1.0f - m4.y) * -10000.0f;
                float ma2 = (1.0f - m4.z) * -10000.0f;
                float ma3 = (1.0f - m4.w) * -10000.0f;
#pragma unroll
                for (int mf = 0; mf < 2; ++mf) {
                    f32x4 sacc = {};
                    sacc = __builtin_amdgcn_mfma_f32_16x16x32_bf16(kb0, qa[mf][0], sacc, 0, 0, 0);  // swapped
                    sacc = __builtin_amdgcn_mfma_f32_16x16x32_bf16(kb1, qa[mf][1], sacc, 0, 0, 0);  // swapped
                    lsum[mf] += (__expf(sacc[0] + ma0) + __expf(sacc[1] + ma1))
                              + (__expf(sacc[2] + ma2) + __expf(sacc[3] + ma3));
                }
            }
        }
        wait_vm0();
        __syncthreads();
        cur ^= 1;
    }
    // lane holds partial sum for q = w*32+mf*16+lr over its lg-subset; reduce across lg groups
#pragma unroll
    for (int mf = 0; mf < 2; ++mf) {
        lsum[mf] += __shfl_xor(lsum[mf], 16);
        lsum[mf] += __shfl_xor(lsum[mf], 32);
    }
    float inv2[2] = {1.0f / lsum[0], 1.0f / lsum[1]};

    // ==== sweep B: p (normalized) -> probs + PV, one pass ====
#pragma unroll
    for (int i = 0; i < 2; ++i) {
        int r = i * 32 + w * 8 + rsub;
        gl2lds16(Kb + r * 64 + jsw, sK + i * 4096 + w * 1024);
        gl2lds16(Vb + r * 2048 + jsw, sV + i * 4096 + w * 1024);
    }
    wait_vm0();
    __syncthreads();

    f32x4 oacc[2][4] = {};
    cur = 0;
    for (int kt = 0; kt < 32; ++kt) {
        char* sKc = sK + cur * 8192;
        char* sVc = sV + cur * 8192;
        if (kt < 31) {
            char* sKn = sK + (cur ^ 1) * 8192;
            char* sVn = sV + (cur ^ 1) * 8192;
            int nt = kt + 1;
#pragma unroll
            for (int i = 0; i < 2; ++i) {
                int r = i * 32 + w * 8 + rsub;
                gl2lds16(Kb + (nt * 64 + r) * 64 + jsw, sKn + i * 4096 + w * 1024);
                gl2lds16(Vb + r * 2048 + nt * 64 + jsw, sVn + i * 4096 + w * 1024);
            }
        }
        // QK^T (swapped) + exp*inv -> packed bf16 sP writes (native RNE casts -> v_cvt_pk)
#pragma unroll
        for (int n16 = 0; n16 < 4; ++n16) {
            int krow = n16 * 16 + lr;
            bf16x8 kb0 = *(const bf16x8*)(sKc + ((krow * 128 + (lg * 8) * 2) ^ ((krow & 7) << 4)));
            bf16x8 kb1 = *(const bf16x8*)(sKc + ((krow * 128 + (32 + lg * 8) * 2) ^ ((krow & 7) << 4)));
            float4 m4 = *(const float4*)(mb + kt * 64 + n16 * 16 + lg * 4);
            float ma0 = (1.0f - m4.x) * -10000.0f;
            float ma1 = (1.0f - m4.y) * -10000.0f;
            float ma2 = (1.0f - m4.z) * -10000.0f;
            float ma3 = (1.0f - m4.w) * -10000.0f;
#pragma unroll
            for (int mf = 0; mf < 2; ++mf) {
                f32x4 sacc = {};
                sacc = __builtin_amdgcn_mfma_f32_16x16x32_bf16(kb0, qa[mf][0], sacc, 0, 0, 0);  // swapped
                sacc = __builtin_amdgcn_mfma_f32_16x16x32_bf16(kb1, qa[mf][1], sacc, 0, 0, 0);  // swapped
                ushort_t tmp[4] __attribute__((aligned(8)));
                tmp[0] = f2bf_native(__expf(sacc[0] + ma0) * inv2[mf]);
                tmp[1] = f2bf_native(__expf(sacc[1] + ma1) * inv2[mf]);
                tmp[2] = f2bf_native(__expf(sacc[2] + ma2) * inv2[mf]);
                tmp[3] = f2bf_native(__expf(sacc[3] + ma3) * inv2[mf]);
                *(uint2*)(sP + w * 4096 + mf * 2048 +
                          ((lr * 128 + n16 * 32 + lg * 8) ^ ((lr & 7) << 4))) = *(uint2*)tmp;
            }
        }
        // probs FIRST (nontemporal): stores drain under the PV MFMA below; NT keeps K/V in L2
#pragma unroll
        for (int mf = 0; mf < 2; ++mf)
#pragma unroll
            for (int step = 0; step < 4; ++step) {
                int srow = step * 4 + lg;
                uint2 uu = *(const uint2*)(sP + w * 4096 + mf * 2048 +
                                           ((srow * 128 + lr * 8) ^ ((srow & 7) << 4)));
                f32x4 pv;
                pv[0] = __uint_as_float((uu.x & 0xffffu) << 16);
                pv[1] = __uint_as_float(uu.x & 0xffff0000u);
                pv[2] = __uint_as_float((uu.y & 0xffffu) << 16);
                pv[3] = __uint_as_float(uu.y & 0xffff0000u);
                __builtin_nontemporal_store(pv,
                    (f32x4*)(prow + (size_t)(q0 + w * 32 + mf * 16 + srow) * 2048 + kt * 64 + lr * 4));
            }
        // PV (byte-identical reads to r4-r20)
        __builtin_amdgcn_s_setprio(1);
#pragma unroll
        for (int mf = 0; mf < 2; ++mf)
#pragma unroll
            for (int kf = 0; kf < 2; ++kf) {
                bf16x8 pa = *(const bf16x8*)(sP + w * 4096 + mf * 2048 +
                                             ((lr * 128 + (kf * 32 + lg * 8) * 2) ^ ((lr & 7) << 4)));
#pragma unroll
                for (int dt = 0; dt < 4; ++dt) {
                    int vrow = dt * 16 + lr;
                    bf16x8 vb = *(const bf16x8*)(sVc + ((vrow * 128 + (kf * 32 + lg * 8) * 2) ^ ((vrow & 7) << 4)));
                    oacc[mf][dt] = __builtin_amdgcn_mfma_f32_16x16x32_bf16(pa, vb, oacc[mf][dt], 0, 0, 0);
                }
            }
        __builtin_amdgcn_s_setprio(0);
        wait_vm8();        // drain gl2lds (older); keep the 8 probs stores in flight
        __syncthreads();
        cur ^= 1;
    }
    // ctx epilogue (nontemporal): p was pre-normalized, so oacc is the final context
#pragma unroll
    for (int mf = 0; mf < 2; ++mf)
#pragma unroll
        for (int dt = 0; dt < 4; ++dt)
#pragma unroll
            for (int r = 0; r < 4; ++r) {
                int qabs = q0 + w * 32 + mf * 16 + lg * 4 + r;
                __builtin_nontemporal_store(oacc[mf][dt][r],
                    ctx + (size_t)(b * 2048 + qabs) * 768 + h * 64 + dt * 16 + lr);
            }
}

extern "C" void kernel_launch(void* const* d_in, const int* in_sizes, int n_in,
                              void* d_out, int out_size, void* d_ws, size_t ws_size,
                              hipStream_t stream) {
    const float* hidden = (const float*)d_in[0];
    const float* mask   = (const float*)d_in[1];
    const float* Wq     = (const float*)d_in[2];
    const float* bq     = (const float*)d_in[3];
    const float* Wk     = (const float*)d_in[4];
    const float* bk     = (const float*)d_in[5];
    const float* Wv     = (const float*)d_in[6];
    const float* bv     = (const float*)d_in[7];
    float* ctx   = (float*)d_out;
    float* probs = ctx + 6291456;

    char* ws = (char*)d_ws;
    ushort_t* hidB = (ushort_t*)(ws);                 // 12.58 MB
    ushort_t* WtB  = (ushort_t*)(ws + 12582912);      // 3.54 MB
    ushort_t* qsB  = (ushort_t*)(ws + 16121856);      // 12.58 MB
    ushort_t* ksB  = (ushort_t*)(ws + 28704768);      // 12.58 MB
    ushort_t* vtB  = (ushort_t*)(ws + 41287680);      // 12.58 MB (V written pre-transposed)

    hipLaunchKernelGGL(prep, dim3(6576), dim3(256), 0, stream, hidden, Wq, Wk, Wv, hidB, WtB);
    hipLaunchKernelGGL(qkv_gemm, dim3(64, 6, 3), dim3(256), 0, stream,
                       hidB, WtB, bq, bk, bv, qsB, ksB, vtB);
    hipLaunchKernelGGL(attn_fused, dim3(768), dim3(256), 0, stream, qsB, ksB, vtB, mask, ctx, probs);
}

// Round 22
// 235.427 us; speedup vs baseline: 1.4033x; 1.0477x over previous
//
#include <hip/hip_runtime.h>
#include <hip/hip_bf16.h>
#include <cstdint>

typedef short bf16x8 __attribute__((ext_vector_type(8)));
typedef float f32x4 __attribute__((ext_vector_type(4)));
typedef unsigned short ushort_t;

__device__ __forceinline__ ushort_t f2bf(float f) {
    uint32_t u = __float_as_uint(f);
    u = (u + 0x7fffu + ((u >> 16) & 1u)) >> 16;
    return (ushort_t)u;
}

// native RNE cast; compiler fuses adjacent pairs into v_cvt_pk_bf16_f32 (m240: beats inline asm)
__device__ __forceinline__ ushort_t f2bf_native(float f) {
    __hip_bfloat16 h = __float2bfloat16(f);
    return *reinterpret_cast<ushort_t*>(&h);
}

// async global->LDS, 16B per lane; LDS dest = wave-uniform base + lane*16
__device__ __forceinline__ void gl2lds16(const void* g, void* l) {
    __builtin_amdgcn_global_load_lds((const __attribute__((address_space(1))) void*)(g),
                                     (__attribute__((address_space(3))) void*)(l), 16, 0, 0);
}

__device__ __forceinline__ void wait_vm0() {
    asm volatile("s_waitcnt vmcnt(0)" ::: "memory");
}
// leave the 4 newest vmem ops (probs stores) in flight; older gl2lds drain (FIFO)
__device__ __forceinline__ void wait_vm4() {
    asm volatile("s_waitcnt vmcnt(4)" ::: "memory");
}

// ---------------- fused prep: blocks 0..431 transpose W; blocks 432..6575 convert hidden ----------------
__global__ void prep(const float* __restrict__ hidden, const float* __restrict__ Wq,
                     const float* __restrict__ Wk, const float* __restrict__ Wv,
                     ushort_t* __restrict__ hidB, ushort_t* __restrict__ WtB) {
    __shared__ float tile[64][68];
    int id = blockIdx.x, t = threadIdx.x;
    if (id < 432) {
        int x = id % 12, y = (id / 12) % 12, z = id / 144;
        const float* W = z == 0 ? Wq : (z == 1 ? Wk : Wv);
        int k0 = x * 64, n0 = y * 64;
        for (int i = 0; i < 4; ++i) {
            int e = i * 1024 + t * 4;
            int r = e >> 6, c = e & 63;
            float4 v = *(const float4*)(W + (k0 + r) * 768 + n0 + c);
            *(float4*)(&tile[r][c]) = v;
        }
        __syncthreads();
        ushort_t* o = WtB + z * 589824;
        for (int i = 0; i < 2; ++i) {
            int e = i * 2048 + t * 8;
            int rn = e >> 6, ck = e & 63;
            ushort_t tmp[8] __attribute__((aligned(16)));
            for (int j = 0; j < 8; ++j) tmp[j] = f2bf(tile[ck + j][rn]);
            *(int4*)(o + (n0 + rn) * 768 + k0 + ck) = *(int4*)tmp;
        }
    } else {
        int i = (id - 432) * 256 + t;   // 6144 blocks x 256 = 1572864 float4s exactly
        float4 v = ((const float4*)hidden)[i];
        ushort_t tmp[4] __attribute__((aligned(8)));
        tmp[0] = f2bf(v.x); tmp[1] = f2bf(v.y); tmp[2] = f2bf(v.z); tmp[3] = f2bf(v.w);
        ((uint2*)hidB)[i] = *(uint2*)tmp;
    }
}

// ---------------- QKV GEMM: async gl2lds double-buffered staging, 1 barrier/K-step ----------------
// z==2 (V) writes directly in transposed [bh][d][s] layout (saves the v_transpose pass)
__launch_bounds__(256, 2)
__global__ void qkv_gemm(const ushort_t* __restrict__ A, const ushort_t* __restrict__ Wt,
                         const float* __restrict__ bq, const float* __restrict__ bk,
                         const float* __restrict__ bv,
                         ushort_t* __restrict__ q_out, ushort_t* __restrict__ k_out,
                         ushort_t* __restrict__ vt_out) {
    __shared__ char smem[65536];
    char* sA = smem;            // 2 x 16KB
    char* sB = smem + 32768;    // 2 x 16KB
    int z = blockIdx.z;
    const ushort_t* Wz = Wt + z * 589824;
    const float* bias = z == 0 ? bq : (z == 1 ? bk : bv);
    int m0 = blockIdx.x * 128, n0 = blockIdx.y * 128;
    int t = threadIdx.x, lane = t & 63, w = t >> 6;
    int wr = w >> 1, wc = w & 1;
    int lr = lane & 15, lg = lane >> 4;
    int rsub = lane >> 3;                    // row-in-8 for this lane's 16B chunk
    int jsw  = ((lane & 7) ^ rsub) * 8;      // pre-swizzled source column (elements)

    // prologue: stage K-step 0 (A-tile 128x64 + B-tile 128x64, 16KB each)
#pragma unroll
    for (int i = 0; i < 4; ++i) {
        int r = i * 32 + w * 8 + rsub;
        gl2lds16(A + (m0 + r) * 768 + jsw, sA + i * 4096 + w * 1024);
        gl2lds16(Wz + (n0 + r) * 768 + jsw, sB + i * 4096 + w * 1024);
    }
    wait_vm0();
    __syncthreads();

    f32x4 acc[4][4] = {};
    int cur = 0;
    for (int ktile = 0; ktile < 12; ++ktile) {
        char* sAc = sA + cur * 16384;
        char* sBc = sB + cur * 16384;
        if (ktile < 11) {
            char* sAn = sA + (cur ^ 1) * 16384;
            char* sBn = sB + (cur ^ 1) * 16384;
            int kt = (ktile + 1) * 64;
#pragma unroll
            for (int i = 0; i < 4; ++i) {
                int r = i * 32 + w * 8 + rsub;
                gl2lds16(A + (m0 + r) * 768 + kt + jsw, sAn + i * 4096 + w * 1024);
                gl2lds16(Wz + (n0 + r) * 768 + kt + jsw, sBn + i * 4096 + w * 1024);
            }
        }
        bf16x8 af[2][4], bfr[2][4];
#pragma unroll
        for (int kf = 0; kf < 2; ++kf)
#pragma unroll
            for (int mf = 0; mf < 4; ++mf) {
                int row = wr * 64 + mf * 16 + lr;
                af[kf][mf] = *(const bf16x8*)(sAc + ((row * 128 + (kf * 32 + lg * 8) * 2) ^ ((row & 7) << 4)));
            }
#pragma unroll
        for (int kf = 0; kf < 2; ++kf)
#pragma unroll
            for (int nf = 0; nf < 4; ++nf) {
                int row = wc * 64 + nf * 16 + lr;
                bfr[kf][nf] = *(const bf16x8*)(sBc + ((row * 128 + (kf * 32 + lg * 8) * 2) ^ ((row & 7) << 4)));
            }
        __builtin_amdgcn_s_setprio(1);
#pragma unroll
        for (int kf = 0; kf < 2; ++kf)
#pragma unroll
            for (int mf = 0; mf < 4; ++mf)
#pragma unroll
                for (int nf = 0; nf < 4; ++nf)
                    acc[mf][nf] = __builtin_amdgcn_mfma_f32_16x16x32_bf16(af[kf][mf], bfr[kf][nf], acc[mf][nf], 0, 0, 0);
        __builtin_amdgcn_s_setprio(0);
        wait_vm0();
        __syncthreads();
        cur ^= 1;
    }
    if (z == 2) {
        // V: write transposed vt[bh][d][s]; thread's 4 rr values are s-consecutive -> 8B packed store
        for (int nf = 0; nf < 4; ++nf) {
            int n = n0 + wc * 64 + nf * 16 + lr;
            float bv_ = bias[n];
            int h = n >> 6, d = n & 63;
            for (int mf = 0; mf < 4; ++mf) {
                int m = m0 + wr * 64 + mf * 16 + lg * 4;
                int b = m >> 11, s = m & 2047;
                ushort_t tmp[4] __attribute__((aligned(8)));
                for (int rr = 0; rr < 4; ++rr) tmp[rr] = f2bf(acc[mf][nf][rr] + bv_);
                *(uint2*)(vt_out + ((size_t)(b * 12 + h) * 64 + d) * 2048 + s) = *(uint2*)tmp;
            }
        }
    } else {
        ushort_t* outp = z == 0 ? q_out : k_out;
        float scale = z == 0 ? 0.125f : 1.0f;
        for (int nf = 0; nf < 4; ++nf) {
            int n = n0 + wc * 64 + nf * 16 + lr;
            float bv_ = bias[n];
            int h = n >> 6, d = n & 63;
            for (int mf = 0; mf < 4; ++mf) {
                for (int rr = 0; rr < 4; ++rr) {
                    int m = m0 + wr * 64 + mf * 16 + lg * 4 + rr;
                    float val = (acc[mf][nf][rr] + bv_) * scale;
                    int b = m >> 11, s = m & 2047;
                    outp[((b * 12 + h) * 2048 + s) * 64 + d] = f2bf(val);
                }
            }
        }
    }
}

// ---------------- fused attention, 3-phase mf pipeline ----------------
// Phase A: lsum(mf0) only (paired K staging). Phase B: probs+PV for mf0 (NT stores) with
// lsum(mf1) MFMA+exp interleaved per-n16 -- mf1's "sweep0" hides under mf0's write stream.
// Phase C: probs+PV for mf1. Swapped mfma(K,Q); all building blocks byte-identical to r21.
// 1-D grid with XCD-aware swizzle (768 % 8 == 0 -> bijective).
__launch_bounds__(256, 3)
__global__ void attn_fused(const ushort_t* __restrict__ qs, const ushort_t* __restrict__ ks,
                           const ushort_t* __restrict__ vt, const float* __restrict__ mask,
                           float* __restrict__ ctx, float* __restrict__ probs) {
    __shared__ char smem[49152];
    char* sK = smem;            // B/C: 2 x 8KB K dbuf (also Q staging); A: pair-buffer 0 (16KB)
    char* sV = smem + 16384;    // B/C: 2 x 8KB V dbuf; A: pair-buffer 1 (16KB)
    char* sP = smem + 32768;    // B/C: 4 waves x 4KB (only first 2KB per wave used per phase)
    int id = blockIdx.x;
    int nid = (id & 7) * 96 + (id >> 3);   // XCD swizzle: 8 XCDs x 96 blocks
    int qt = nid & 15, bh = nid >> 4;
    int b = bh / 12, h = bh % 12;
    int q0 = qt * 128;
    int t = threadIdx.x, lane = t & 63, w = t >> 6;
    int lr = lane & 15, lg = lane >> 4;
    const ushort_t* Qb = qs + bh * 131072;
    const ushort_t* Kb = ks + bh * 131072;
    const ushort_t* Vb = vt + bh * 131072;
    const float* mb = mask + b * 2048;
    float* prow = probs + (size_t)bh * 4194304;

    int rsub = lane >> 3;                    // row-in-8 for this lane's 16B chunk
    int jsw  = ((lane & 7) ^ rsub) * 8;      // pre-swizzled source column (elements)

    // stage Q (128x64 = 16KB) into sK area, linear LDS + swizzled source
#pragma unroll
    for (int i = 0; i < 4; ++i) {
        int r = i * 32 + w * 8 + rsub;
        gl2lds16(Qb + (q0 + r) * 64 + jsw, sK + i * 4096 + w * 1024);
    }
    wait_vm0();
    __syncthreads();
    bf16x8 qa[2][2];
#pragma unroll
    for (int mf = 0; mf < 2; ++mf)
#pragma unroll
        for (int kf = 0; kf < 2; ++kf) {
            int row = w * 32 + mf * 16 + lr;
            qa[mf][kf] = *(const bf16x8*)(sK + ((row * 128 + (kf * 32 + lg * 8) * 2) ^ ((row & 7) << 4)));
        }
    __syncthreads();

    // ==== Phase A: lsum for mf0, 2 K-tiles per staging round (16 barriers) ====
#pragma unroll
    for (int t2 = 0; t2 < 2; ++t2)
#pragma unroll
        for (int i = 0; i < 2; ++i) {
            int r = t2 * 64 + i * 32 + w * 8 + rsub;
            gl2lds16(Kb + r * 64 + jsw, smem + t2 * 8192 + i * 4096 + w * 1024);
        }
    wait_vm0();
    __syncthreads();
    float lsum0 = 0.f, lsum1 = 0.f;
    int cur = 0;
    for (int kp = 0; kp < 16; ++kp) {
        char* bufc = smem + cur * 16384;
        if (kp < 15) {
            char* bufn = smem + (cur ^ 1) * 16384;
#pragma unroll
            for (int t2 = 0; t2 < 2; ++t2)
#pragma unroll
                for (int i = 0; i < 2; ++i) {
                    int r = ((kp + 1) * 2 + t2) * 64 + i * 32 + w * 8 + rsub;
                    gl2lds16(Kb + r * 64 + jsw, bufn + t2 * 8192 + i * 4096 + w * 1024);
                }
        }
#pragma unroll
        for (int t2 = 0; t2 < 2; ++t2) {
            int kt = kp * 2 + t2;
            char* sKc = bufc + t2 * 8192;
#pragma unroll
            for (int n16 = 0; n16 < 4; ++n16) {
                int krow = n16 * 16 + lr;
                bf16x8 kb0 = *(const bf16x8*)(sKc + ((krow * 128 + (lg * 8) * 2) ^ ((krow & 7) << 4)));
                bf16x8 kb1 = *(const bf16x8*)(sKc + ((krow * 128 + (32 + lg * 8) * 2) ^ ((krow & 7) << 4)));
                float4 m4 = *(const float4*)(mb + kt * 64 + n16 * 16 + lg * 4);
                float ma0 = (1.0f - m4.x) * -10000.0f;
                float ma1 = (1.0f - m4.y) * -10000.0f;
                float ma2 = (1.0f - m4.z) * -10000.0f;
                float ma3 = (1.0f - m4.w) * -10000.0f;
                f32x4 sacc = {};
                sacc = __builtin_amdgcn_mfma_f32_16x16x32_bf16(kb0, qa[0][0], sacc, 0, 0, 0);  // swapped
                sacc = __builtin_amdgcn_mfma_f32_16x16x32_bf16(kb1, qa[0][1], sacc, 0, 0, 0);  // swapped
                lsum0 += (__expf(sacc[0] + ma0) + __expf(sacc[1] + ma1))
                       + (__expf(sacc[2] + ma2) + __expf(sacc[3] + ma3));
            }
        }
        wait_vm0();
        __syncthreads();
        cur ^= 1;
    }
    lsum0 += __shfl_xor(lsum0, 16);
    lsum0 += __shfl_xor(lsum0, 32);
    float inv0 = 1.0f / lsum0;

    // ==== Phase B: probs+PV for mf0 (NT stores) + lsum(mf1) interleaved ====
#pragma unroll
    for (int i = 0; i < 2; ++i) {
        int r = i * 32 + w * 8 + rsub;
        gl2lds16(Kb + r * 64 + jsw, sK + i * 4096 + w * 1024);
        gl2lds16(Vb + r * 2048 + jsw, sV + i * 4096 + w * 1024);
    }
    wait_vm0();
    __syncthreads();
    f32x4 oacc[4] = {};
    cur = 0;
    for (int kt = 0; kt < 32; ++kt) {
        char* sKc = sK + cur * 8192;
        char* sVc = sV + cur * 8192;
        if (kt < 31) {
            char* sKn = sK + (cur ^ 1) * 8192;
            char* sVn = sV + (cur ^ 1) * 8192;
            int nt = kt + 1;
#pragma unroll
            for (int i = 0; i < 2; ++i) {
                int r = i * 32 + w * 8 + rsub;
                gl2lds16(Kb + (nt * 64 + r) * 64 + jsw, sKn + i * 4096 + w * 1024);
                gl2lds16(Vb + r * 2048 + nt * 64 + jsw, sVn + i * 4096 + w * 1024);
            }
        }
#pragma unroll
        for (int n16 = 0; n16 < 4; ++n16) {
            int krow = n16 * 16 + lr;
            bf16x8 kb0 = *(const bf16x8*)(sKc + ((krow * 128 + (lg * 8) * 2) ^ ((krow & 7) << 4)));
            bf16x8 kb1 = *(const bf16x8*)(sKc + ((krow * 128 + (32 + lg * 8) * 2) ^ ((krow & 7) << 4)));
            float4 m4 = *(const float4*)(mb + kt * 64 + n16 * 16 + lg * 4);
            float ma0 = (1.0f - m4.x) * -10000.0f;
            float ma1 = (1.0f - m4.y) * -10000.0f;
            float ma2 = (1.0f - m4.z) * -10000.0f;
            float ma3 = (1.0f - m4.w) * -10000.0f;
            // mf0: normalized p -> sP (wave slot 0)
            {
                f32x4 sacc = {};
                sacc = __builtin_amdgcn_mfma_f32_16x16x32_bf16(kb0, qa[0][0], sacc, 0, 0, 0);  // swapped
                sacc = __builtin_amdgcn_mfma_f32_16x16x32_bf16(kb1, qa[0][1], sacc, 0, 0, 0);  // swapped
                ushort_t tmp[4] __attribute__((aligned(8)));
                tmp[0] = f2bf_native(__expf(sacc[0] + ma0) * inv0);
                tmp[1] = f2bf_native(__expf(sacc[1] + ma1) * inv0);
                tmp[2] = f2bf_native(__expf(sacc[2] + ma2) * inv0);
                tmp[3] = f2bf_native(__expf(sacc[3] + ma3) * inv0);
                *(uint2*)(sP + w * 4096 +
                          ((lr * 128 + n16 * 32 + lg * 8) ^ ((lr & 7) << 4))) = *(uint2*)tmp;
            }
            // mf1: lsum accumulation (hides under mf0's store stream)
            {
                f32x4 sacc = {};
                sacc = __builtin_amdgcn_mfma_f32_16x16x32_bf16(kb0, qa[1][0], sacc, 0, 0, 0);  // swapped
                sacc = __builtin_amdgcn_mfma_f32_16x16x32_bf16(kb1, qa[1][1], sacc, 0, 0, 0);  // swapped
                lsum1 += (__expf(sacc[0] + ma0) + __expf(sacc[1] + ma1))
                       + (__expf(sacc[2] + ma2) + __expf(sacc[3] + ma3));
            }
        }
        // probs (mf0) nontemporal stores: drain under the PV MFMA below
#pragma unroll
        for (int step = 0; step < 4; ++step) {
            int srow = step * 4 + lg;
            uint2 uu = *(const uint2*)(sP + w * 4096 +
                                       ((srow * 128 + lr * 8) ^ ((srow & 7) << 4)));
            f32x4 pv;
            pv[0] = __uint_as_float((uu.x & 0xffffu) << 16);
            pv[1] = __uint_as_float(uu.x & 0xffff0000u);
            pv[2] = __uint_as_float((uu.y & 0xffffu) << 16);
            pv[3] = __uint_as_float(uu.y & 0xffff0000u);
            __builtin_nontemporal_store(pv,
                (f32x4*)(prow + (size_t)(q0 + w * 32 + srow) * 2048 + kt * 64 + lr * 4));
        }
        // PV mf0
        __builtin_amdgcn_s_setprio(1);
#pragma unroll
        for (int kf = 0; kf < 2; ++kf) {
            bf16x8 pa = *(const bf16x8*)(sP + w * 4096 +
                                         ((lr * 128 + (kf * 32 + lg * 8) * 2) ^ ((lr & 7) << 4)));
#pragma unroll
            for (int dt = 0; dt < 4; ++dt) {
                int vrow = dt * 16 + lr;
                bf16x8 vb = *(const bf16x8*)(sVc + ((vrow * 128 + (kf * 32 + lg * 8) * 2) ^ ((vrow & 7) << 4)));
                oacc[dt] = __builtin_amdgcn_mfma_f32_16x16x32_bf16(pa, vb, oacc[dt], 0, 0, 0);
            }
        }
        __builtin_amdgcn_s_setprio(0);
        wait_vm4();        // drain gl2lds (older); keep the 4 probs stores in flight
        __syncthreads();
        cur ^= 1;
    }
    lsum1 += __shfl_xor(lsum1, 16);
    lsum1 += __shfl_xor(lsum1, 32);
    float inv1 = 1.0f / lsum1;
    // ctx (mf0), nontemporal
#pragma unroll
    for (int dt = 0; dt < 4; ++dt)
#pragma unroll
        for (int r = 0; r < 4; ++r) {
            int qabs = q0 + w * 32 + lg * 4 + r;
            __builtin_nontemporal_store(oacc[dt][r],
                ctx + (size_t)(b * 2048 + qabs) * 768 + h * 64 + dt * 16 + lr);
        }

    // ==== Phase C: probs+PV for mf1 ====
#pragma unroll
    for (int dt = 0; dt < 4; ++dt) oacc[dt] = (f32x4){0.f, 0.f, 0.f, 0.f};
#pragma unroll
    for (int i = 0; i < 2; ++i) {
        int r = i * 32 + w * 8 + rsub;
        gl2lds16(Kb + r * 64 + jsw, sK + i * 4096 + w * 1024);
        gl2lds16(Vb + r * 2048 + jsw, sV + i * 4096 + w * 1024);
    }
    wait_vm0();
    __syncthreads();
    cur = 0;
    for (int kt = 0; kt < 32; ++kt) {
        char* sKc = sK + cur * 8192;
        char* sVc = sV + cur * 8192;
        if (kt < 31) {
            char* sKn = sK + (cur ^ 1) * 8192;
            char* sVn = sV + (cur ^ 1) * 8192;
            int nt = kt + 1;
#pragma unroll
            for (int i = 0; i < 2; ++i) {
                int r = i * 32 + w * 8 + rsub;
                gl2lds16(Kb + (nt * 64 + r) * 64 + jsw, sKn + i * 4096 + w * 1024);
                gl2lds16(Vb + r * 2048 + nt * 64 + jsw, sVn + i * 4096 + w * 1024);
            }
        }
#pragma unroll
        for (int n16 = 0; n16 < 4; ++n16) {
            int krow = n16 * 16 + lr;
            bf16x8 kb0 = *(const bf16x8*)(sKc + ((krow * 128 + (lg * 8) * 2) ^ ((krow & 7) << 4)));
            bf16x8 kb1 = *(const bf16x8*)(sKc + ((krow * 128 + (32 + lg * 8) * 2) ^ ((krow & 7) << 4)));
            float4 m4 = *(const float4*)(mb + kt * 64 + n16 * 16 + lg * 4);
            float ma0 = (1.0f - m4.x) * -10000.0f;
            float ma1 = (1.0f - m4.y) * -10000.0f;
            float ma2 = (1.0f - m4.z) * -10000.0f;
            float ma3 = (1.0f - m4.w) * -10000.0f;
            f32x4 sacc = {};
            sacc = __builtin_amdgcn_mfma_f32_16x16x32_bf16(kb0, qa[1][0], sacc, 0, 0, 0);  // swapped
            sacc = __builtin_amdgcn_mfma_f32_16x16x32_bf16(kb1, qa[1][1], sacc, 0, 0, 0);  // swapped
            ushort_t tmp[4] __attribute__((aligned(8)));
            tmp[0] = f2bf_native(__expf(sacc[0] + ma0) * inv1);
            tmp[1] = f2bf_native(__expf(sacc[1] + ma1) * inv1);
            tmp[2] = f2bf_native(__expf(sacc[2] + ma2) * inv1);
            tmp[3] = f2bf_native(__expf(sacc[3] + ma3) * inv1);
            *(uint2*)(sP + w * 4096 +
                      ((lr * 128 + n16 * 32 + lg * 8) ^ ((lr & 7) << 4))) = *(uint2*)tmp;
        }
        // probs (mf1) nontemporal stores
#pragma unroll
        for (int step = 0; step < 4; ++step) {
            int srow = step * 4 + lg;
            uint2 uu = *(const uint2*)(sP + w * 4096 +
                                       ((srow * 128 + lr * 8) ^ ((srow & 7) << 4)));
            f32x4 pv;
            pv[0] = __uint_as_float((uu.x & 0xffffu) << 16);
            pv[1] = __uint_as_float(uu.x & 0xffff0000u);
            pv[2] = __uint_as_float((uu.y & 0xffffu) << 16);
            pv[3] = __uint_as_float(uu.y & 0xffff0000u);
            __builtin_nontemporal_store(pv,
                (f32x4*)(prow + (size_t)(q0 + w * 32 + 16 + srow) * 2048 + kt * 64 + lr * 4));
        }
        // PV mf1
        __builtin_amdgcn_s_setprio(1);
#pragma unroll
        for (int kf = 0; kf < 2; ++kf) {
            bf16x8 pa = *(const bf16x8*)(sP + w * 4096 +
                                         ((lr * 128 + (kf * 32 + lg * 8) * 2) ^ ((lr & 7) << 4)));
#pragma unroll
            for (int dt = 0; dt < 4; ++dt) {
                int vrow = dt * 16 + lr;
                bf16x8 vb = *(const bf16x8*)(sVc + ((vrow * 128 + (kf * 32 + lg * 8) * 2) ^ ((vrow & 7) << 4)));
                oacc[dt] = __builtin_amdgcn_mfma_f32_16x16x32_bf16(pa, vb, oacc[dt], 0, 0, 0);
            }
        }
        __builtin_amdgcn_s_setprio(0);
        wait_vm4();
        __syncthreads();
        cur ^= 1;
    }
    // ctx (mf1), nontemporal
#pragma unroll
    for (int dt = 0; dt < 4; ++dt)
#pragma unroll
        for (int r = 0; r < 4; ++r) {
            int qabs = q0 + w * 32 + 16 + lg * 4 + r;
            __builtin_nontemporal_store(oacc[dt][r],
                ctx + (size_t)(b * 2048 + qabs) * 768 + h * 64 + dt * 16 + lr);
        }
}

extern "C" void kernel_launch(void* const* d_in, const int* in_sizes, int n_in,
                              void* d_out, int out_size, void* d_ws, size_t ws_size,
                              hipStream_t stream) {
    const float* hidden = (const float*)d_in[0];
    const float* mask   = (const float*)d_in[1];
    const float* Wq     = (const float*)d_in[2];
    const float* bq     = (const float*)d_in[3];
    const float* Wk     = (const float*)d_in[4];
    const float* bk     = (const float*)d_in[5];
    const float* Wv     = (const float*)d_in[6];
    const float* bv     = (const float*)d_in[7];
    float* ctx   = (float*)d_out;
    float* probs = ctx + 6291456;

    char* ws = (char*)d_ws;
    ushort_t* hidB = (ushort_t*)(ws);                 // 12.58 MB
    ushort_t* WtB  = (ushort_t*)(ws + 12582912);      // 3.54 MB
    ushort_t* qsB  = (ushort_t*)(ws + 16121856);      // 12.58 MB
    ushort_t* ksB  = (ushort_t*)(ws + 28704768);      // 12.58 MB
    ushort_t* vtB  = (ushort_t*)(ws + 41287680);      // 12.58 MB (V written pre-transposed)

    hipLaunchKernelGGL(prep, dim3(6576), dim3(256), 0, stream, hidden, Wq, Wk, Wv, hidB, WtB);
    hipLaunchKernelGGL(qkv_gemm, dim3(64, 6, 3), dim3(256), 0, stream,
                       hidB, WtB, bq, bk, bv, qsB, ksB, vtB);
    hipLaunchKernelGGL(attn_fused, dim3(768), dim3(256), 0, stream, qsB, ksB, vtB, mask, ctx, probs);
}

// Round 23
// 230.237 us; speedup vs baseline: 1.4349x; 1.0225x over previous
//
#include <hip/hip_runtime.h>
#include <hip/hip_bf16.h>
#include <cstdint>

typedef short bf16x8 __attribute__((ext_vector_type(8)));
typedef float f32x4 __attribute__((ext_vector_type(4)));
typedef unsigned short ushort_t;

__device__ __forceinline__ ushort_t f2bf(float f) {
    uint32_t u = __float_as_uint(f);
    u = (u + 0x7fffu + ((u >> 16) & 1u)) >> 16;
    return (ushort_t)u;
}

// native RNE cast; compiler fuses adjacent pairs into v_cvt_pk_bf16_f32 (m240: beats inline asm)
__device__ __forceinline__ ushort_t f2bf_native(float f) {
    __hip_bfloat16 h = __float2bfloat16(f);
    return *reinterpret_cast<ushort_t*>(&h);
}

// async global->LDS, 16B per lane; LDS dest = wave-uniform base + lane*16
__device__ __forceinline__ void gl2lds16(const void* g, void* l) {
    __builtin_amdgcn_global_load_lds((const __attribute__((address_space(1))) void*)(g),
                                     (__attribute__((address_space(3))) void*)(l), 16, 0, 0);
}

__device__ __forceinline__ void wait_vm0() {
    asm volatile("s_waitcnt vmcnt(0)" ::: "memory");
}
// counted barrier (T4/m201): drain gl2lds (older) + all LDS ops, keep the 4 NT stores in flight
__device__ __forceinline__ void barrier_vm4() {
    asm volatile("s_waitcnt vmcnt(4) lgkmcnt(0)" ::: "memory");
    __builtin_amdgcn_s_barrier();
    __builtin_amdgcn_sched_barrier(0);
}

// ---------------- fused prep: blocks 0..431 transpose W; blocks 432..6575 convert hidden ----------------
__global__ void prep(const float* __restrict__ hidden, const float* __restrict__ Wq,
                     const float* __restrict__ Wk, const float* __restrict__ Wv,
                     ushort_t* __restrict__ hidB, ushort_t* __restrict__ WtB) {
    __shared__ float tile[64][68];
    int id = blockIdx.x, t = threadIdx.x;
    if (id < 432) {
        int x = id % 12, y = (id / 12) % 12, z = id / 144;
        const float* W = z == 0 ? Wq : (z == 1 ? Wk : Wv);
        int k0 = x * 64, n0 = y * 64;
        for (int i = 0; i < 4; ++i) {
            int e = i * 1024 + t * 4;
            int r = e >> 6, c = e & 63;
            float4 v = *(const float4*)(W + (k0 + r) * 768 + n0 + c);
            *(float4*)(&tile[r][c]) = v;
        }
        __syncthreads();
        ushort_t* o = WtB + z * 589824;
        for (int i = 0; i < 2; ++i) {
            int e = i * 2048 + t * 8;
            int rn = e >> 6, ck = e & 63;
            ushort_t tmp[8] __attribute__((aligned(16)));
            for (int j = 0; j < 8; ++j) tmp[j] = f2bf(tile[ck + j][rn]);
            *(int4*)(o + (n0 + rn) * 768 + k0 + ck) = *(int4*)tmp;
        }
    } else {
        int i = (id - 432) * 256 + t;   // 6144 blocks x 256 = 1572864 float4s exactly
        float4 v = ((const float4*)hidden)[i];
        ushort_t tmp[4] __attribute__((aligned(8)));
        tmp[0] = f2bf(v.x); tmp[1] = f2bf(v.y); tmp[2] = f2bf(v.z); tmp[3] = f2bf(v.w);
        ((uint2*)hidB)[i] = *(uint2*)tmp;
    }
}

// ---------------- QKV GEMM: async gl2lds double-buffered staging, 1 barrier/K-step ----------------
// z==2 (V) writes directly in transposed [bh][d][s] layout (saves the v_transpose pass)
__launch_bounds__(256, 2)
__global__ void qkv_gemm(const ushort_t* __restrict__ A, const ushort_t* __restrict__ Wt,
                         const float* __restrict__ bq, const float* __restrict__ bk,
                         const float* __restrict__ bv,
                         ushort_t* __restrict__ q_out, ushort_t* __restrict__ k_out,
                         ushort_t* __restrict__ vt_out) {
    __shared__ char smem[65536];
    char* sA = smem;            // 2 x 16KB
    char* sB = smem + 32768;    // 2 x 16KB
    int z = blockIdx.z;
    const ushort_t* Wz = Wt + z * 589824;
    const float* bias = z == 0 ? bq : (z == 1 ? bk : bv);
    int m0 = blockIdx.x * 128, n0 = blockIdx.y * 128;
    int t = threadIdx.x, lane = t & 63, w = t >> 6;
    int wr = w >> 1, wc = w & 1;
    int lr = lane & 15, lg = lane >> 4;
    int rsub = lane >> 3;                    // row-in-8 for this lane's 16B chunk
    int jsw  = ((lane & 7) ^ rsub) * 8;      // pre-swizzled source column (elements)

    // prologue: stage K-step 0 (A-tile 128x64 + B-tile 128x64, 16KB each)
#pragma unroll
    for (int i = 0; i < 4; ++i) {
        int r = i * 32 + w * 8 + rsub;
        gl2lds16(A + (m0 + r) * 768 + jsw, sA + i * 4096 + w * 1024);
        gl2lds16(Wz + (n0 + r) * 768 + jsw, sB + i * 4096 + w * 1024);
    }
    wait_vm0();
    __syncthreads();

    f32x4 acc[4][4] = {};
    int cur = 0;
    for (int ktile = 0; ktile < 12; ++ktile) {
        char* sAc = sA + cur * 16384;
        char* sBc = sB + cur * 16384;
        if (ktile < 11) {
            char* sAn = sA + (cur ^ 1) * 16384;
            char* sBn = sB + (cur ^ 1) * 16384;
            int kt = (ktile + 1) * 64;
#pragma unroll
            for (int i = 0; i < 4; ++i) {
                int r = i * 32 + w * 8 + rsub;
                gl2lds16(A + (m0 + r) * 768 + kt + jsw, sAn + i * 4096 + w * 1024);
                gl2lds16(Wz + (n0 + r) * 768 + kt + jsw, sBn + i * 4096 + w * 1024);
            }
        }
        bf16x8 af[2][4], bfr[2][4];
#pragma unroll
        for (int kf = 0; kf < 2; ++kf)
#pragma unroll
            for (int mf = 0; mf < 4; ++mf) {
                int row = wr * 64 + mf * 16 + lr;
                af[kf][mf] = *(const bf16x8*)(sAc + ((row * 128 + (kf * 32 + lg * 8) * 2) ^ ((row & 7) << 4)));
            }
#pragma unroll
        for (int kf = 0; kf < 2; ++kf)
#pragma unroll
            for (int nf = 0; nf < 4; ++nf) {
                int row = wc * 64 + nf * 16 + lr;
                bfr[kf][nf] = *(const bf16x8*)(sBc + ((row * 128 + (kf * 32 + lg * 8) * 2) ^ ((row & 7) << 4)));
            }
        __builtin_amdgcn_s_setprio(1);
#pragma unroll
        for (int kf = 0; kf < 2; ++kf)
#pragma unroll
            for (int mf = 0; mf < 4; ++mf)
#pragma unroll
                for (int nf = 0; nf < 4; ++nf)
                    acc[mf][nf] = __builtin_amdgcn_mfma_f32_16x16x32_bf16(af[kf][mf], bfr[kf][nf], acc[mf][nf], 0, 0, 0);
        __builtin_amdgcn_s_setprio(0);
        wait_vm0();
        __syncthreads();
        cur ^= 1;
    }
    if (z == 2) {
        // V: write transposed vt[bh][d][s]; thread's 4 rr values are s-consecutive -> 8B packed store
        for (int nf = 0; nf < 4; ++nf) {
            int n = n0 + wc * 64 + nf * 16 + lr;
            float bv_ = bias[n];
            int h = n >> 6, d = n & 63;
            for (int mf = 0; mf < 4; ++mf) {
                int m = m0 + wr * 64 + mf * 16 + lg * 4;
                int b = m >> 11, s = m & 2047;
                ushort_t tmp[4] __attribute__((aligned(8)));
                for (int rr = 0; rr < 4; ++rr) tmp[rr] = f2bf(acc[mf][nf][rr] + bv_);
                *(uint2*)(vt_out + ((size_t)(b * 12 + h) * 64 + d) * 2048 + s) = *(uint2*)tmp;
            }
        }
    } else {
        ushort_t* outp = z == 0 ? q_out : k_out;
        float scale = z == 0 ? 0.125f : 1.0f;
        for (int nf = 0; nf < 4; ++nf) {
            int n = n0 + wc * 64 + nf * 16 + lr;
            float bv_ = bias[n];
            int h = n >> 6, d = n & 63;
            for (int mf = 0; mf < 4; ++mf) {
                for (int rr = 0; rr < 4; ++rr) {
                    int m = m0 + wr * 64 + mf * 16 + lg * 4 + rr;
                    float val = (acc[mf][nf][rr] + bv_) * scale;
                    int b = m >> 11, s = m & 2047;
                    outp[((b * 12 + h) * 2048 + s) * 64 + d] = f2bf(val);
                }
            }
        }
    }
}

// ---------------- fused attention, 3-phase mf pipeline ----------------
// Mask bias precomputed into an LDS table (madd) so NO vmem loads pollute the vmcnt FIFO:
// gl2lds prefetch genuinely stays in flight through compute, and counted barriers (vmcnt(4))
// keep the 4 NT probs stores in flight across iterations (T4/m201 pattern).
// LDS map: [0,16K) sK dbuf (A: pair-buf 0) | [16,32K) sV dbuf (A: pair-buf 1)
//          [32,40K) sP 4 waves x 2KB | [40,48K) madd table (2048 f32, persists all phases)
__launch_bounds__(256, 3)
__global__ void attn_fused(const ushort_t* __restrict__ qs, const ushort_t* __restrict__ ks,
                           const ushort_t* __restrict__ vt, const float* __restrict__ mask,
                           float* __restrict__ ctx, float* __restrict__ probs) {
    __shared__ char smem[49152];
    char* sK = smem;
    char* sV = smem + 16384;
    char* sP = smem + 32768;
    float* smadd = (float*)(smem + 40960);
    int id = blockIdx.x;
    int nid = (id & 7) * 96 + (id >> 3);   // XCD swizzle: 8 XCDs x 96 blocks
    int qt = nid & 15, bh = nid >> 4;
    int b = bh / 12, h = bh % 12;
    int q0 = qt * 128;
    int t = threadIdx.x, lane = t & 63, w = t >> 6;
    int lr = lane & 15, lg = lane >> 4;
    const ushort_t* Qb = qs + bh * 131072;
    const ushort_t* Kb = ks + bh * 131072;
    const ushort_t* Vb = vt + bh * 131072;
    const float* mb = mask + b * 2048;
    float* prow = probs + (size_t)bh * 4194304;

    int rsub = lane >> 3;                    // row-in-8 for this lane's 16B chunk
    int jsw  = ((lane & 7) ^ rsub) * 8;      // pre-swizzled source column (elements)

    // stage Q (128x64 = 16KB) into sK area + build madd table
#pragma unroll
    for (int i = 0; i < 4; ++i) {
        int r = i * 32 + w * 8 + rsub;
        gl2lds16(Qb + (q0 + r) * 64 + jsw, sK + i * 4096 + w * 1024);
    }
    {
        float4 mv0 = *(const float4*)(mb + t * 8);
        float4 mv1 = *(const float4*)(mb + t * 8 + 4);
        f32x4 a0, a1;
        a0[0] = (1.0f - mv0.x) * -10000.0f; a0[1] = (1.0f - mv0.y) * -10000.0f;
        a0[2] = (1.0f - mv0.z) * -10000.0f; a0[3] = (1.0f - mv0.w) * -10000.0f;
        a1[0] = (1.0f - mv1.x) * -10000.0f; a1[1] = (1.0f - mv1.y) * -10000.0f;
        a1[2] = (1.0f - mv1.z) * -10000.0f; a1[3] = (1.0f - mv1.w) * -10000.0f;
        *(f32x4*)(smadd + t * 8) = a0;
        *(f32x4*)(smadd + t * 8 + 4) = a1;
    }
    wait_vm0();
    __syncthreads();
    bf16x8 qa[2][2];
#pragma unroll
    for (int mf = 0; mf < 2; ++mf)
#pragma unroll
        for (int kf = 0; kf < 2; ++kf) {
            int row = w * 32 + mf * 16 + lr;
            qa[mf][kf] = *(const bf16x8*)(sK + ((row * 128 + (kf * 32 + lg * 8) * 2) ^ ((row & 7) << 4)));
        }
    __syncthreads();

    // ==== Phase A: lsum for mf0, 2 K-tiles per staging round (16 barriers) ====
#pragma unroll
    for (int t2 = 0; t2 < 2; ++t2)
#pragma unroll
        for (int i = 0; i < 2; ++i) {
            int r = t2 * 64 + i * 32 + w * 8 + rsub;
            gl2lds16(Kb + r * 64 + jsw, smem + t2 * 8192 + i * 4096 + w * 1024);
        }
    wait_vm0();
    __syncthreads();
    float lsum0 = 0.f, lsum1 = 0.f;
    int cur = 0;
    for (int kp = 0; kp < 16; ++kp) {
        char* bufc = smem + cur * 16384;
        if (kp < 15) {
            char* bufn = smem + (cur ^ 1) * 16384;
#pragma unroll
            for (int t2 = 0; t2 < 2; ++t2)
#pragma unroll
                for (int i = 0; i < 2; ++i) {
                    int r = ((kp + 1) * 2 + t2) * 64 + i * 32 + w * 8 + rsub;
                    gl2lds16(Kb + r * 64 + jsw, bufn + t2 * 8192 + i * 4096 + w * 1024);
                }
        }
#pragma unroll
        for (int t2 = 0; t2 < 2; ++t2) {
            int kt = kp * 2 + t2;
            char* sKc = bufc + t2 * 8192;
#pragma unroll
            for (int n16 = 0; n16 < 4; ++n16) {
                int krow = n16 * 16 + lr;
                bf16x8 kb0 = *(const bf16x8*)(sKc + ((krow * 128 + (lg * 8) * 2) ^ ((krow & 7) << 4)));
                bf16x8 kb1 = *(const bf16x8*)(sKc + ((krow * 128 + (32 + lg * 8) * 2) ^ ((krow & 7) << 4)));
                f32x4 m4 = *(const f32x4*)(smadd + kt * 64 + n16 * 16 + lg * 4);
                f32x4 sacc = {};
                sacc = __builtin_amdgcn_mfma_f32_16x16x32_bf16(kb0, qa[0][0], sacc, 0, 0, 0);  // swapped
                sacc = __builtin_amdgcn_mfma_f32_16x16x32_bf16(kb1, qa[0][1], sacc, 0, 0, 0);  // swapped
                lsum0 += (__expf(sacc[0] + m4[0]) + __expf(sacc[1] + m4[1]))
                       + (__expf(sacc[2] + m4[2]) + __expf(sacc[3] + m4[3]));
            }
        }
        wait_vm0();
        __syncthreads();
        cur ^= 1;
    }
    lsum0 += __shfl_xor(lsum0, 16);
    lsum0 += __shfl_xor(lsum0, 32);
    float inv0 = 1.0f / lsum0;

    // ==== Phase B: probs+PV for mf0 (NT stores) + lsum(mf1) interleaved ====
#pragma unroll
    for (int i = 0; i < 2; ++i) {
        int r = i * 32 + w * 8 + rsub;
        gl2lds16(Kb + r * 64 + jsw, sK + i * 4096 + w * 1024);
        gl2lds16(Vb + r * 2048 + jsw, sV + i * 4096 + w * 1024);
    }
    wait_vm0();
    __syncthreads();
    f32x4 oacc[4] = {};
    cur = 0;
    for (int kt = 0; kt < 32; ++kt) {
        char* sKc = sK + cur * 8192;
        char* sVc = sV + cur * 8192;
        if (kt < 31) {
            char* sKn = sK + (cur ^ 1) * 8192;
            char* sVn = sV + (cur ^ 1) * 8192;
            int nt = kt + 1;
#pragma unroll
            for (int i = 0; i < 2; ++i) {
                int r = i * 32 + w * 8 + rsub;
                gl2lds16(Kb + (nt * 64 + r) * 64 + jsw, sKn + i * 4096 + w * 1024);
                gl2lds16(Vb + r * 2048 + nt * 64 + jsw, sVn + i * 4096 + w * 1024);
            }
        }
#pragma unroll
        for (int n16 = 0; n16 < 4; ++n16) {
            int krow = n16 * 16 + lr;
            bf16x8 kb0 = *(const bf16x8*)(sKc + ((krow * 128 + (lg * 8) * 2) ^ ((krow & 7) << 4)));
            bf16x8 kb1 = *(const bf16x8*)(sKc + ((krow * 128 + (32 + lg * 8) * 2) ^ ((krow & 7) << 4)));
            f32x4 m4 = *(const f32x4*)(smadd + kt * 64 + n16 * 16 + lg * 4);
            // mf0: normalized p -> sP (wave slot)
            {
                f32x4 sacc = {};
                sacc = __builtin_amdgcn_mfma_f32_16x16x32_bf16(kb0, qa[0][0], sacc, 0, 0, 0);  // swapped
                sacc = __builtin_amdgcn_mfma_f32_16x16x32_bf16(kb1, qa[0][1], sacc, 0, 0, 0);  // swapped
                ushort_t tmp[4] __attribute__((aligned(8)));
                tmp[0] = f2bf_native(__expf(sacc[0] + m4[0]) * inv0);
                tmp[1] = f2bf_native(__expf(sacc[1] + m4[1]) * inv0);
                tmp[2] = f2bf_native(__expf(sacc[2] + m4[2]) * inv0);
                tmp[3] = f2bf_native(__expf(sacc[3] + m4[3]) * inv0);
                *(uint2*)(sP + w * 2048 +
                          ((lr * 128 + n16 * 32 + lg * 8) ^ ((lr & 7) << 4))) = *(uint2*)tmp;
            }
            // mf1: lsum accumulation (hides under mf0's store stream)
            {
                f32x4 sacc = {};
                sacc = __builtin_amdgcn_mfma_f32_16x16x32_bf16(kb0, qa[1][0], sacc, 0, 0, 0);  // swapped
                sacc = __builtin_amdgcn_mfma_f32_16x16x32_bf16(kb1, qa[1][1], sacc, 0, 0, 0);  // swapped
                lsum1 += (__expf(sacc[0] + m4[0]) + __expf(sacc[1] + m4[1]))
                       + (__expf(sacc[2] + m4[2]) + __expf(sacc[3] + m4[3]));
            }
        }
        // probs (mf0) nontemporal stores: drain under the PV MFMA below
#pragma unroll
        for (int step = 0; step < 4; ++step) {
            int srow = step * 4 + lg;
            uint2 uu = *(const uint2*)(sP + w * 2048 +
                                       ((srow * 128 + lr * 8) ^ ((srow & 7) << 4)));
            f32x4 pv;
            pv[0] = __uint_as_float((uu.x & 0xffffu) << 16);
            pv[1] = __uint_as_float(uu.x & 0xffff0000u);
            pv[2] = __uint_as_float((uu.y & 0xffffu) << 16);
            pv[3] = __uint_as_float(uu.y & 0xffff0000u);
            __builtin_nontemporal_store(pv,
                (f32x4*)(prow + (size_t)(q0 + w * 32 + srow) * 2048 + kt * 64 + lr * 4));
        }
        // PV mf0
        __builtin_amdgcn_s_setprio(1);
#pragma unroll
        for (int kf = 0; kf < 2; ++kf) {
            bf16x8 pa = *(const bf16x8*)(sP + w * 2048 +
                                         ((lr * 128 + (kf * 32 + lg * 8) * 2) ^ ((lr & 7) << 4)));
#pragma unroll
            for (int dt = 0; dt < 4; ++dt) {
                int vrow = dt * 16 + lr;
                bf16x8 vb = *(const bf16x8*)(sVc + ((vrow * 128 + (kf * 32 + lg * 8) * 2) ^ ((vrow & 7) << 4)));
                oacc[dt] = __builtin_amdgcn_mfma_f32_16x16x32_bf16(pa, vb, oacc[dt], 0, 0, 0);
            }
        }
        __builtin_amdgcn_s_setprio(0);
        barrier_vm4();     // counted barrier: gl2lds drained, 4 NT stores stay in flight
        cur ^= 1;
    }
    lsum1 += __shfl_xor(lsum1, 16);
    lsum1 += __shfl_xor(lsum1, 32);
    float inv1 = 1.0f / lsum1;
    // ctx (mf0), nontemporal
#pragma unroll
    for (int dt = 0; dt < 4; ++dt)
#pragma unroll
        for (int r = 0; r < 4; ++r) {
            int qabs = q0 + w * 32 + lg * 4 + r;
            __builtin_nontemporal_store(oacc[dt][r],
                ctx + (size_t)(b * 2048 + qabs) * 768 + h * 64 + dt * 16 + lr);
        }

    // ==== Phase C: probs+PV for mf1 ====
#pragma unroll
    for (int dt = 0; dt < 4; ++dt) oacc[dt] = (f32x4){0.f, 0.f, 0.f, 0.f};
#pragma unroll
    for (int i = 0; i < 2; ++i) {
        int r = i * 32 + w * 8 + rsub;
        gl2lds16(Kb + r * 64 + jsw, sK + i * 4096 + w * 1024);
        gl2lds16(Vb + r * 2048 + jsw, sV + i * 4096 + w * 1024);
    }
    wait_vm0();
    __syncthreads();
    cur = 0;
    for (int kt = 0; kt < 32; ++kt) {
        char* sKc = sK + cur * 8192;
        char* sVc = sV + cur * 8192;
        if (kt < 31) {
            char* sKn = sK + (cur ^ 1) * 8192;
            char* sVn = sV + (cur ^ 1) * 8192;
            int nt = kt + 1;
#pragma unroll
            for (int i = 0; i < 2; ++i) {
                int r = i * 32 + w * 8 + rsub;
                gl2lds16(Kb + (nt * 64 + r) * 64 + jsw, sKn + i * 4096 + w * 1024);
                gl2lds16(Vb + r * 2048 + nt * 64 + jsw, sVn + i * 4096 + w * 1024);
            }
        }
#pragma unroll
        for (int n16 = 0; n16 < 4; ++n16) {
            int krow = n16 * 16 + lr;
            bf16x8 kb0 = *(const bf16x8*)(sKc + ((krow * 128 + (lg * 8) * 2) ^ ((krow & 7) << 4)));
            bf16x8 kb1 = *(const bf16x8*)(sKc + ((krow * 128 + (32 + lg * 8) * 2) ^ ((krow & 7) << 4)));
            f32x4 m4 = *(const f32x4*)(smadd + kt * 64 + n16 * 16 + lg * 4);
            f32x4 sacc = {};
            sacc = __builtin_amdgcn_mfma_f32_16x16x32_bf16(kb0, qa[1][0], sacc, 0, 0, 0);  // swapped
            sacc = __builtin_amdgcn_mfma_f32_16x16x32_bf16(kb1, qa[1][1], sacc, 0, 0, 0);  // swapped
            ushort_t tmp[4] __attribute__((aligned(8)));
            tmp[0] = f2bf_native(__expf(sacc[0] + m4[0]) * inv1);
            tmp[1] = f2bf_native(__expf(sacc[1] + m4[1]) * inv1);
            tmp[2] = f2bf_native(__expf(sacc[2] + m4[2]) * inv1);
            tmp[3] = f2bf_native(__expf(sacc[3] + m4[3]) * inv1);
            *(uint2*)(sP + w * 2048 +
                      ((lr * 128 + n16 * 32 + lg * 8) ^ ((lr & 7) << 4))) = *(uint2*)tmp;
        }
        // probs (mf1) nontemporal stores
#pragma unroll
        for (int step = 0; step < 4; ++step) {
            int srow = step * 4 + lg;
            uint2 uu = *(const uint2*)(sP + w * 2048 +
                                       ((srow * 128 + lr * 8) ^ ((srow & 7) << 4)));
            f32x4 pv;
            pv[0] = __uint_as_float((uu.x & 0xffffu) << 16);
            pv[1] = __uint_as_float(uu.x & 0xffff0000u);
            pv[2] = __uint_as_float((uu.y & 0xffffu) << 16);
            pv[3] = __uint_as_float(uu.y & 0xffff0000u);
            __builtin_nontemporal_store(pv,
                (f32x4*)(prow + (size_t)(q0 + w * 32 + 16 + srow) * 2048 + kt * 64 + lr * 4));
        }
        // PV mf1
        __builtin_amdgcn_s_setprio(1);
#pragma unroll
        for (int kf = 0; kf < 2; ++kf) {
            bf16x8 pa = *(const bf16x8*)(sP + w * 2048 +
                                         ((lr * 128 + (kf * 32 + lg * 8) * 2) ^ ((lr & 7) << 4)));
#pragma unroll
            for (int dt = 0; dt < 4; ++dt) {
                int vrow = dt * 16 + lr;
                bf16x8 vb = *(const bf16x8*)(sVc + ((vrow * 128 + (kf * 32 + lg * 8) * 2) ^ ((vrow & 7) << 4)));
                oacc[dt] = __builtin_amdgcn_mfma_f32_16x16x32_bf16(pa, vb, oacc[dt], 0, 0, 0);
            }
        }
        __builtin_amdgcn_s_setprio(0);
        barrier_vm4();
        cur ^= 1;
    }
    // ctx (mf1), nontemporal
#pragma unroll
    for (int dt = 0; dt < 4; ++dt)
#pragma unroll
        for (int r = 0; r < 4; ++r) {
            int qabs = q0 + w * 32 + 16 + lg * 4 + r;
            __builtin_nontemporal_store(oacc[dt][r],
                ctx + (size_t)(b * 2048 + qabs) * 768 + h * 64 + dt * 16 + lr);
        }
}

extern "C" void kernel_launch(void* const* d_in, const int* in_sizes, int n_in,
                              void* d_out, int out_size, void* d_ws, size_t ws_size,
                              hipStream_t stream) {
    const float* hidden = (const float*)d_in[0];
    const float* mask   = (const float*)d_in[1];
    const float* Wq     = (const float*)d_in[2];
    const float* bq     = (const float*)d_in[3];
    const float* Wk     = (const float*)d_in[4];
    const float* bk     = (const float*)d_in[5];
    const float* Wv     = (const float*)d_in[6];
    const float* bv     = (const float*)d_in[7];
    float* ctx   = (float*)d_out;
    float* probs = ctx + 6291456;

    char* ws = (char*)d_ws;
    ushort_t* hidB = (ushort_t*)(ws);                 // 12.58 MB
    ushort_t* WtB  = (ushort_t*)(ws + 12582912);      // 3.54 MB
    ushort_t* qsB  = (ushort_t*)(ws + 16121856);      // 12.58 MB
    ushort_t* ksB  = (ushort_t*)(ws + 28704768);      // 12.58 MB
    ushort_t* vtB  = (ushort_t*)(ws + 41287680);      // 12.58 MB (V written pre-transposed)

    hipLaunchKernelGGL(prep, dim3(6576), dim3(256), 0, stream, hidden, Wq, Wk, Wv, hidB, WtB);
    hipLaunchKernelGGL(qkv_gemm, dim3(64, 6, 3), dim3(256), 0, stream,
                       hidB, WtB, bq, bk, bv, qsB, ksB, vtB);
    hipLaunchKernelGGL(attn_fused, dim3(768), dim3(256), 0, stream, qsB, ksB, vtB, mask, ctx, probs);
}